// Round 8
// baseline (499.987 us; speedup 1.0000x reference)
//
#include <hip/hip_runtime.h>
#include <math.h>

#define NB    8
#define CDIM  256
#define NN    2304
#define NH    4
#define DH    32
#define HIDC  128
#define OC3   384
#define SCALE_LOG2E 0.25503524964550864f         // 32^-0.5 * log2(e)
#define SEG   2359296                            // NB*NH*NN*DH
#define LSEG  73728                              // NB*NH*NN
#define PPARTS 4
#define JCHUNK 576                               // NN / PPARTS
#define NITER  18                               // JCHUNK / 32
#define GRID  576    // persistent blocks; capacity >= 768 (VGPR<=168, LDS 17.7KB) => co-resident

typedef short  bf16x8 __attribute__((ext_vector_type(8)));
typedef float  f32x4  __attribute__((ext_vector_type(4)));

__device__ __forceinline__ unsigned short f2bf(float f) {
    union { float f; unsigned u; } a; a.f = f;
    unsigned r = a.u + 0x7fffu + ((a.u >> 16) & 1u);   // RNE
    return (unsigned short)(r >> 16);
}

__device__ __forceinline__ unsigned pack_trunc(float lo, float hi) {
    union { float f; unsigned u; } a, b; a.f = lo; b.f = hi;
    return (b.u & 0xFFFF0000u) | (a.u >> 16);          // bf16x2, truncated
}

__device__ __forceinline__ float bflo(unsigned u) {
    union { unsigned u; float f; } c; c.u = u << 16; return c.f;
}
__device__ __forceinline__ float bfhi(unsigned u) {
    union { unsigned u; float f; } c; c.u = u & 0xFFFF0000u; return c.f;
}

// ---------------------------------------------------------------------------
// Manual grid barrier (plain launch, graph-capturable).  Counters are
// hipMemsetAsync-zeroed at the start of every kernel_launch, so each graph
// replay sees a fresh barrier.  Co-residency guaranteed by launch_bounds
// (VGPR<=168 => 3 blocks/CU => capacity 768 >= GRID 576) -> no deadlock.
// __syncthreads drains the block's vmcnt; __threadfence is an agent-scope
// fence (L2 writeback / invalidate on gfx950) for cross-XCD visibility.
// ---------------------------------------------------------------------------
__device__ __forceinline__ void grid_bar(unsigned* cnt, unsigned n) {
    __syncthreads();
    if (threadIdx.x == 0) {
        __threadfence();
        __hip_atomic_fetch_add(cnt, 1u, __ATOMIC_RELEASE, __HIP_MEMORY_SCOPE_AGENT);
        while (__hip_atomic_load(cnt, __ATOMIC_ACQUIRE, __HIP_MEMORY_SCOPE_AGENT) < n)
            __builtin_amdgcn_s_sleep(8);
        __threadfence();
    }
    __syncthreads();
}

// ---------------------------------------------------------------------------
// Phase 1 body: QKV projection (r6 o-split form, 864 tasks).
// ---------------------------------------------------------------------------
__device__ __forceinline__ void qkv_body(
    int Lb, unsigned short* As, unsigned short* Bs,
    const float* __restrict__ x, const float* __restrict__ w,
    unsigned short* __restrict__ qt, unsigned short* __restrict__ kt,
    unsigned short* __restrict__ vtT)
{
    const int xcd  = Lb & 7;
    const int t    = Lb >> 3;            // 0..107
    const int so   = t % 6;              // o-tile (sel*2 + half)
    const int gl   = t / 6;              // 0..17
    const int group = gl * 8 + xcd;      // 0..143
    const int nb   = group % 18;
    const int b    = group / 18;
    const int n0 = nb * 128;
    const int o0 = so * 64;
    const int sel = so >> 1;             // 0=q 1=k 2=v

    const int tid  = (int)threadIdx.x;
    const int wave = tid >> 6;
    const int lane = tid & 63;
    const int li   = lane & 15;
    const int g    = lane >> 4;
    const int wm = (wave & 1) * 32;
    const int wn = (wave >> 1) * 64;
    const float* xb = x + (size_t)b * CDIM * NN;

    const int aco = (tid & 7) * 4;
    const int aor = tid >> 3;
    const int n4  = (tid & 31) * 4;
    const int c4  = (tid >> 5) * 4;

    f32x4 acc[2][4];
#pragma unroll
    for (int i = 0; i < 2; ++i)
#pragma unroll
        for (int j = 0; j < 4; ++j) acc[i][j] = (f32x4){0.f, 0.f, 0.f, 0.f};

    float4 wv[2], xv[4];
#pragma unroll
    for (int r = 0; r < 2; ++r)
        wv[r] = *(const float4*)&w[(size_t)(o0 + aor + 32 * r) * CDIM + aco];
#pragma unroll
    for (int dd = 0; dd < 4; ++dd)
        xv[dd] = *(const float4*)&xb[(size_t)(c4 + dd) * NN + n0 + n4];

    for (int k0 = 0; k0 < CDIM; k0 += 32) {
        __syncthreads();
#pragma unroll
        for (int r = 0; r < 2; ++r) {
            uint2 pk;
            pk.x = (unsigned)f2bf(wv[r].x) | ((unsigned)f2bf(wv[r].y) << 16);
            pk.y = (unsigned)f2bf(wv[r].z) | ((unsigned)f2bf(wv[r].w) << 16);
            *(uint2*)&As[(aor + 32 * r) * 40 + aco] = pk;
        }
#pragma unroll
        for (int j = 0; j < 4; ++j) {
            uint2 pk;
            pk.x = (unsigned)f2bf(((const float*)&xv[0])[j])
                 | ((unsigned)f2bf(((const float*)&xv[1])[j]) << 16);
            pk.y = (unsigned)f2bf(((const float*)&xv[2])[j])
                 | ((unsigned)f2bf(((const float*)&xv[3])[j]) << 16);
            *(uint2*)&Bs[(n4 + j) * 40 + c4] = pk;
        }
        __syncthreads();

        const int kn = (k0 + 32 < CDIM) ? (k0 + 32) : k0;
#pragma unroll
        for (int r = 0; r < 2; ++r)
            wv[r] = *(const float4*)&w[(size_t)(o0 + aor + 32 * r) * CDIM + kn + aco];
#pragma unroll
        for (int dd = 0; dd < 4; ++dd)
            xv[dd] = *(const float4*)&xb[(size_t)(kn + c4 + dd) * NN + n0 + n4];

        bf16x8 af[2], bfr[4];
#pragma unroll
        for (int mt = 0; mt < 2; ++mt)
            af[mt] = *(const bf16x8*)&As[(wm + mt * 16 + li) * 40 + g * 8];
#pragma unroll
        for (int nt = 0; nt < 4; ++nt)
            bfr[nt] = *(const bf16x8*)&Bs[(wn + nt * 16 + li) * 40 + g * 8];
#pragma unroll
        for (int mt = 0; mt < 2; ++mt)
#pragma unroll
            for (int nt = 0; nt < 4; ++nt)
                acc[mt][nt] = __builtin_amdgcn_mfma_f32_16x16x32_bf16(
                    af[mt], bfr[nt], acc[mt][nt], 0, 0, 0);
    }

    if (sel < 2) {
        unsigned short* dst = (sel == 0) ? qt : kt;
        const float mul = (sel == 0) ? SCALE_LOG2E : 1.0f;
#pragma unroll
        for (int mt = 0; mt < 2; ++mt) {
            const int ob = o0 + wm + mt * 16 + g * 4;
            const int d0 = ob & 31;
            const int h  = (ob & 127) >> 5;
            const size_t bh = (size_t)(b * NH + h);
#pragma unroll
            for (int nt = 0; nt < 4; ++nt) {
                const int n = n0 + wn + nt * 16 + li;
                const f32x4 a = acc[mt][nt];
                uint2 pk;
                pk.x = (unsigned)f2bf(a[0] * mul) | ((unsigned)f2bf(a[1] * mul) << 16);
                pk.y = (unsigned)f2bf(a[2] * mul) | ((unsigned)f2bf(a[3] * mul) << 16);
                *(uint2*)&dst[(bh * NN + n) * DH + d0] = pk;
            }
        }
    } else {
#pragma unroll
        for (int mt = 0; mt < 2; ++mt) {
            const int ob = o0 + wm + mt * 16 + g * 4;
            const int d0 = ob & 31;
            const int h  = (ob & 127) >> 5;
            const size_t bh = (size_t)(b * NH + h);
#pragma unroll
            for (int nt = 0; nt < 4; ++nt) {
                const int n = n0 + wn + nt * 16 + li;
                const f32x4 a = acc[mt][nt];
#pragma unroll
                for (int r = 0; r < 4; ++r)
                    vtT[(bh * DH + d0 + r) * (size_t)NN + n] = f2bf(a[r]);
            }
        }
    }
}

// ---------------------------------------------------------------------------
// Phase 2 body: flash attention (r5 form: 4 Q-frags/wave, 2-deep K/V
// prefetch, LDS P-relayout, O^T epilogue; 1152 tasks).  Pl is per-wave.
// ---------------------------------------------------------------------------
__device__ __forceinline__ void attn_body(
    int Lb, unsigned short* Pl,
    const unsigned short* __restrict__ qt, const unsigned short* __restrict__ kt,
    const unsigned short* __restrict__ vtT, unsigned short* __restrict__ Op,
    float* __restrict__ Lp)
{
    const int xcd = Lb & 7;
    const int t   = Lb >> 3;                  // 0..143
    const int ib  = t % 9;                    // i-block (256 rows)
    const int grp = (t / 9) * 8 + xcd;        // 0..127
    const int bh  = grp >> 2;
    const int part = grp & 3;
    const int jbeg = part * JCHUNK;

    const int tid  = (int)threadIdx.x;
    const int wave = tid >> 6;
    const int lane = tid & 63;
    const int li   = lane & 15;
    const int g    = lane >> 4;
    const int i0   = ib * 256 + wave * 64;

    const unsigned short* qb = qt  + (size_t)bh * NN * DH;
    const unsigned short* kb = kt  + (size_t)bh * NN * DH;
    const unsigned short* vb = vtT + (size_t)bh * DH * NN;

    bf16x8 qfA = *(const bf16x8*)(qb + (size_t)(i0 + li) * DH + g * 8);
    bf16x8 qfB = *(const bf16x8*)(qb + (size_t)(i0 + 16 + li) * DH + g * 8);
    bf16x8 qfC = *(const bf16x8*)(qb + (size_t)(i0 + 32 + li) * DH + g * 8);
    bf16x8 qfD = *(const bf16x8*)(qb + (size_t)(i0 + 48 + li) * DH + g * 8);

    bf16x8 ones;
#pragma unroll
    for (int r = 0; r < 8; ++r) ones[r] = (short)0x3F80;

    f32x4 O0A = {0.f,0.f,0.f,0.f}, O1A = {0.f,0.f,0.f,0.f}, LsA = {0.f,0.f,0.f,0.f};
    f32x4 O0B = {0.f,0.f,0.f,0.f}, O1B = {0.f,0.f,0.f,0.f}, LsB = {0.f,0.f,0.f,0.f};
    f32x4 O0C = {0.f,0.f,0.f,0.f}, O1C = {0.f,0.f,0.f,0.f}, LsC = {0.f,0.f,0.f,0.f};
    f32x4 O0D = {0.f,0.f,0.f,0.f}, O1D = {0.f,0.f,0.f,0.f}, LsD = {0.f,0.f,0.f,0.f};

    unsigned short* plA = Pl + wave * 2048;
    unsigned short* plB = plA + 512;
    unsigned short* plC = plA + 1024;
    unsigned short* plD = plA + 1536;
    const int sw  = li & 6;
    const int pw  = li * 32;
    const int wr0 = pw + ((g ^ sw) << 2);
    const int wr1 = pw + (((4 + g) ^ sw) << 2);
    const int rdo = pw + (((2 * g) ^ sw) << 2);

    const unsigned short* kp0 = kb + (size_t)(jbeg + li) * DH + g * 8;
    const unsigned short* kp1 = kp0 + 16 * DH;
    const unsigned short* vp0 = vb + (size_t)li * NN + jbeg + g * 8;
    const unsigned short* vp1 = vp0 + 16 * NN;

    bf16x8 kf0A = *(const bf16x8*)kp0;
    bf16x8 kf1A = *(const bf16x8*)kp1;
    bf16x8 vf0A = *(const bf16x8*)vp0;
    bf16x8 vf1A = *(const bf16x8*)vp1;
    bf16x8 kf0B = *(const bf16x8*)(kp0 + 32 * DH);
    bf16x8 kf1B = *(const bf16x8*)(kp1 + 32 * DH);
    bf16x8 vf0B = *(const bf16x8*)(vp0 + 32);
    bf16x8 vf1B = *(const bf16x8*)(vp1 + 32);
    kp0 += 64 * DH; kp1 += 64 * DH;
    vp0 += 64;      vp1 += 64;

#define ATTN_ITER(KF0, KF1, VF0, VF1)                                          \
    do {                                                                       \
        f32x4 z = {0.f, 0.f, 0.f, 0.f};                                        \
        f32x4 s0A = __builtin_amdgcn_mfma_f32_16x16x32_bf16(KF0, qfA, z, 0, 0, 0); \
        f32x4 s0B = __builtin_amdgcn_mfma_f32_16x16x32_bf16(KF0, qfB, z, 0, 0, 0); \
        f32x4 s0C = __builtin_amdgcn_mfma_f32_16x16x32_bf16(KF0, qfC, z, 0, 0, 0); \
        f32x4 s0D = __builtin_amdgcn_mfma_f32_16x16x32_bf16(KF0, qfD, z, 0, 0, 0); \
        f32x4 s1A = __builtin_amdgcn_mfma_f32_16x16x32_bf16(KF1, qfA, z, 0, 0, 0); \
        f32x4 s1B = __builtin_amdgcn_mfma_f32_16x16x32_bf16(KF1, qfB, z, 0, 0, 0); \
        f32x4 s1C = __builtin_amdgcn_mfma_f32_16x16x32_bf16(KF1, qfC, z, 0, 0, 0); \
        f32x4 s1D = __builtin_amdgcn_mfma_f32_16x16x32_bf16(KF1, qfD, z, 0, 0, 0); \
        KF0 = *(const bf16x8*)kp0;                                             \
        KF1 = *(const bf16x8*)kp1;                                             \
        kp0 += 32 * DH; kp1 += 32 * DH;                                        \
        float p0A[4], p1A[4], p0B[4], p1B[4];                                  \
        float p0C[4], p1C[4], p0D[4], p1D[4];                                  \
        _Pragma("unroll")                                                      \
        for (int r = 0; r < 4; ++r) {                                          \
            p0A[r] = __builtin_amdgcn_exp2f(s0A[r]);                           \
            p1A[r] = __builtin_amdgcn_exp2f(s1A[r]);                           \
            p0B[r] = __builtin_amdgcn_exp2f(s0B[r]);                           \
            p1B[r] = __builtin_amdgcn_exp2f(s1B[r]);                           \
            p0C[r] = __builtin_amdgcn_exp2f(s0C[r]);                           \
            p1C[r] = __builtin_amdgcn_exp2f(s1C[r]);                           \
            p0D[r] = __builtin_amdgcn_exp2f(s0D[r]);                           \
            p1D[r] = __builtin_amdgcn_exp2f(s1D[r]);                           \
        }                                                                      \
        uint2 wa, wb;                                                          \
        wa.x = pack_trunc(p0A[0], p0A[1]);  wa.y = pack_trunc(p0A[2], p0A[3]); \
        wb.x = pack_trunc(p1A[0], p1A[1]);  wb.y = pack_trunc(p1A[2], p1A[3]); \
        *(uint2*)&plA[wr0] = wa;                                               \
        *(uint2*)&plA[wr1] = wb;                                               \
        wa.x = pack_trunc(p0B[0], p0B[1]);  wa.y = pack_trunc(p0B[2], p0B[3]); \
        wb.x = pack_trunc(p1B[0], p1B[1]);  wb.y = pack_trunc(p1B[2], p1B[3]); \
        *(uint2*)&plB[wr0] = wa;                                               \
        *(uint2*)&plB[wr1] = wb;                                               \
        wa.x = pack_trunc(p0C[0], p0C[1]);  wa.y = pack_trunc(p0C[2], p0C[3]); \
        wb.x = pack_trunc(p1C[0], p1C[1]);  wb.y = pack_trunc(p1C[2], p1C[3]); \
        *(uint2*)&plC[wr0] = wa;                                               \
        *(uint2*)&plC[wr1] = wb;                                               \
        wa.x = pack_trunc(p0D[0], p0D[1]);  wa.y = pack_trunc(p0D[2], p0D[3]); \
        wb.x = pack_trunc(p1D[0], p1D[1]);  wb.y = pack_trunc(p1D[2], p1D[3]); \
        *(uint2*)&plD[wr0] = wa;                                               \
        *(uint2*)&plD[wr1] = wb;                                               \
        bf16x8 pfA = *(const bf16x8*)&plA[rdo];                                \
        bf16x8 pfB = *(const bf16x8*)&plB[rdo];                                \
        bf16x8 pfC = *(const bf16x8*)&plC[rdo];                                \
        bf16x8 pfD = *(const bf16x8*)&plD[rdo];                                \
        O0A = __builtin_amdgcn_mfma_f32_16x16x32_bf16(VF0,  pfA, O0A, 0, 0, 0); \
        O0B = __builtin_amdgcn_mfma_f32_16x16x32_bf16(VF0,  pfB, O0B, 0, 0, 0); \
        O0C = __builtin_amdgcn_mfma_f32_16x16x32_bf16(VF0,  pfC, O0C, 0, 0, 0); \
        O0D = __builtin_amdgcn_mfma_f32_16x16x32_bf16(VF0,  pfD, O0D, 0, 0, 0); \
        O1A = __builtin_amdgcn_mfma_f32_16x16x32_bf16(VF1,  pfA, O1A, 0, 0, 0); \
        O1B = __builtin_amdgcn_mfma_f32_16x16x32_bf16(VF1,  pfB, O1B, 0, 0, 0); \
        O1C = __builtin_amdgcn_mfma_f32_16x16x32_bf16(VF1,  pfC, O1C, 0, 0, 0); \
        O1D = __builtin_amdgcn_mfma_f32_16x16x32_bf16(VF1,  pfD, O1D, 0, 0, 0); \
        LsA = __builtin_amdgcn_mfma_f32_16x16x32_bf16(ones, pfA, LsA, 0, 0, 0); \
        LsB = __builtin_amdgcn_mfma_f32_16x16x32_bf16(ones, pfB, LsB, 0, 0, 0); \
        LsC = __builtin_amdgcn_mfma_f32_16x16x32_bf16(ones, pfC, LsC, 0, 0, 0); \
        LsD = __builtin_amdgcn_mfma_f32_16x16x32_bf16(ones, pfD, LsD, 0, 0, 0); \
        VF0 = *(const bf16x8*)vp0;                                             \
        VF1 = *(const bf16x8*)vp1;                                             \
        vp0 += 32; vp1 += 32;                                                  \
    } while (0)

#pragma unroll 1
    for (int it = 0; it < NITER; it += 2) {
        ATTN_ITER(kf0A, kf1A, vf0A, vf1A);
        ATTN_ITER(kf0B, kf1B, vf0B, vf1B);
    }
#undef ATTN_ITER

    unsigned short* obA = Op + (size_t)part * SEG + (size_t)bh * DH * NN + i0 + li;
    unsigned short* obB = obA + 16;
    unsigned short* obC = obA + 32;
    unsigned short* obD = obA + 48;
#pragma unroll
    for (int r = 0; r < 4; ++r) {
        obA[(size_t)(4 * g + r)      * NN] = f2bf(O0A[r]);
        obA[(size_t)(16 + 4 * g + r) * NN] = f2bf(O1A[r]);
        obB[(size_t)(4 * g + r)      * NN] = f2bf(O0B[r]);
        obB[(size_t)(16 + 4 * g + r) * NN] = f2bf(O1B[r]);
        obC[(size_t)(4 * g + r)      * NN] = f2bf(O0C[r]);
        obC[(size_t)(16 + 4 * g + r) * NN] = f2bf(O1C[r]);
        obD[(size_t)(4 * g + r)      * NN] = f2bf(O0D[r]);
        obD[(size_t)(16 + 4 * g + r) * NN] = f2bf(O1D[r]);
    }
    if (g == 0) {
        float* lpb = Lp + (size_t)part * LSEG + (size_t)bh * NN + i0 + li;
        lpb[0]  = LsA[0];
        lpb[16] = LsB[0];
        lpb[32] = LsC[0];
        lpb[48] = LsD[0];
    }
}

// ---------------------------------------------------------------------------
// Phase 3 body: output projection (r6 o-split form, 576 tasks).
// ---------------------------------------------------------------------------
__device__ __forceinline__ void out_body(
    int Lb, unsigned short* As, unsigned short* Bs, float* Linv /*[4][128]*/,
    const unsigned short* __restrict__ Op, const float* __restrict__ Lp,
    const float* __restrict__ w, const float* __restrict__ bias,
    float* __restrict__ y)
{
    const int xcd  = Lb & 7;
    const int t    = Lb >> 3;            // 0..71
    const int so   = t % 4;
    const int gl   = t / 4;              // 0..17
    const int group = gl * 8 + xcd;      // 0..143
    const int nb   = group % 18;
    const int b    = group / 18;
    const int n0 = nb * 128;
    const int o0 = so * 64;

    const int tid  = (int)threadIdx.x;
    const int wave = tid >> 6;
    const int lane = tid & 63;
    const int li   = lane & 15;
    const int g    = lane >> 4;
    const int wm = (wave & 1) * 32;
    const int wn = (wave >> 1) * 64;

    const int aco = (tid & 7) * 4;
    const int aor = tid >> 3;
    const int n4  = (tid & 31) * 4;
    const int d4  = (tid >> 5) * 4;

    {
        const int h = tid >> 6, nb2 = tid & 63;
#pragma unroll
        for (int half = 0; half < 2; ++half) {
            const int n = nb2 + 64 * half;
            float s = 0.f;
#pragma unroll
            for (int p = 0; p < PPARTS; ++p)
                s += Lp[(size_t)p * LSEG + (size_t)(b * NH + h) * NN + n0 + n];
            Linv[h * 128 + n] = 1.0f / s;
        }
    }

    f32x4 acc[2][4];
#pragma unroll
    for (int i = 0; i < 2; ++i)
#pragma unroll
        for (int j = 0; j < 4; ++j) acc[i][j] = (f32x4){0.f, 0.f, 0.f, 0.f};

    float4 wv[2];
    uint2  ov[PPARTS][4];
#pragma unroll
    for (int r = 0; r < 2; ++r)
        wv[r] = *(const float4*)&w[(size_t)(o0 + aor + 32 * r) * HIDC + aco];
    {
        const size_t bh0 = (size_t)(b * NH);
#pragma unroll
        for (int p = 0; p < PPARTS; ++p)
#pragma unroll
            for (int dd = 0; dd < 4; ++dd)
                ov[p][dd] = *(const uint2*)&Op[(size_t)p * SEG
                              + (bh0 * DH + d4 + dd) * (size_t)NN + n0 + n4];
    }

    for (int k0 = 0; k0 < HIDC; k0 += 32) {
        __syncthreads();
#pragma unroll
        for (int r = 0; r < 2; ++r) {
            uint2 pk;
            pk.x = (unsigned)f2bf(wv[r].x) | ((unsigned)f2bf(wv[r].y) << 16);
            pk.y = (unsigned)f2bf(wv[r].z) | ((unsigned)f2bf(wv[r].w) << 16);
            *(uint2*)&As[(aor + 32 * r) * 40 + aco] = pk;
        }
        const int h = k0 >> 5;
        {
            float s[4][4];
#pragma unroll
            for (int dd = 0; dd < 4; ++dd)
#pragma unroll
                for (int j = 0; j < 4; ++j) s[dd][j] = 0.f;
#pragma unroll
            for (int p = 0; p < PPARTS; ++p) {
#pragma unroll
                for (int dd = 0; dd < 4; ++dd) {
                    const uint2 u = ov[p][dd];
                    s[dd][0] += bflo(u.x); s[dd][1] += bfhi(u.x);
                    s[dd][2] += bflo(u.y); s[dd][3] += bfhi(u.y);
                }
            }
#pragma unroll
            for (int j = 0; j < 4; ++j) {
                const float lv = Linv[h * 128 + n4 + j];
                uint2 pk;
                pk.x = (unsigned)f2bf(s[0][j] * lv) | ((unsigned)f2bf(s[1][j] * lv) << 16);
                pk.y = (unsigned)f2bf(s[2][j] * lv) | ((unsigned)f2bf(s[3][j] * lv) << 16);
                *(uint2*)&Bs[(n4 + j) * 40 + d4] = pk;
            }
        }
        __syncthreads();

        const int kn = (k0 + 32 < HIDC) ? (k0 + 32) : k0;
        const size_t bhn = (size_t)(b * NH + (kn >> 5));
#pragma unroll
        for (int r = 0; r < 2; ++r)
            wv[r] = *(const float4*)&w[(size_t)(o0 + aor + 32 * r) * HIDC + kn + aco];
#pragma unroll
        for (int p = 0; p < PPARTS; ++p)
#pragma unroll
            for (int dd = 0; dd < 4; ++dd)
                ov[p][dd] = *(const uint2*)&Op[(size_t)p * SEG
                              + (bhn * DH + d4 + dd) * (size_t)NN + n0 + n4];

        bf16x8 af[2], bfr[4];
#pragma unroll
        for (int mt = 0; mt < 2; ++mt)
            af[mt] = *(const bf16x8*)&As[(wm + mt * 16 + li) * 40 + g * 8];
#pragma unroll
        for (int nt = 0; nt < 4; ++nt)
            bfr[nt] = *(const bf16x8*)&Bs[(wn + nt * 16 + li) * 40 + g * 8];
#pragma unroll
        for (int mt = 0; mt < 2; ++mt)
#pragma unroll
            for (int nt = 0; nt < 4; ++nt)
                acc[mt][nt] = __builtin_amdgcn_mfma_f32_16x16x32_bf16(
                    af[mt], bfr[nt], acc[mt][nt], 0, 0, 0);
    }

#pragma unroll
    for (int mt = 0; mt < 2; ++mt) {
        const int ob = o0 + wm + mt * 16 + g * 4;
        const float b0 = bias[ob], b1 = bias[ob + 1], b2 = bias[ob + 2], b3 = bias[ob + 3];
#pragma unroll
        for (int nt = 0; nt < 4; ++nt) {
            const int n = n0 + wn + nt * 16 + li;
            const f32x4 a = acc[mt][nt];
            float* yb = y + ((size_t)(b * CDIM + ob)) * NN + n;
            yb[0]              = a[0] + b0;
            yb[(size_t)NN]     = a[1] + b1;
            yb[(size_t)2 * NN] = a[2] + b2;
            yb[(size_t)3 * NN] = a[3] + b3;
        }
    }
}

// ---------------------------------------------------------------------------
// Fused persistent kernel with MANUAL grid barriers (no cooperative API —
// round-7's hipLaunchCooperativeKernel silently never ran; plain <<<>>> is
// graph-capturable).  qkv -> bar -> attn -> bar -> out.  Saves 2 kernel
// boundaries (~15 us each, measured round 4) + dispatch ramps.
// ---------------------------------------------------------------------------
__global__ __launch_bounds__(256, 3) void fused_kernel(
    const float* __restrict__ x, const float* __restrict__ w_qkv,
    const float* __restrict__ w_out, const float* __restrict__ b_out,
    float* __restrict__ y,
    unsigned short* qt, unsigned short* kt, unsigned short* vtT,
    unsigned short* Op, float* Lp, unsigned* bar)
{
    __shared__ __align__(16) unsigned char smem[17664];
    const int bid = (int)blockIdx.x;

    {
        unsigned short* As = (unsigned short*)smem;
        unsigned short* Bs = As + 64 * 40;
#pragma unroll 1
        for (int task = bid; task < 864; task += GRID)
            qkv_body(task, As, Bs, x, w_qkv, qt, kt, vtT);
    }
    grid_bar(&bar[0], GRID);
    {
        unsigned short* Pl = (unsigned short*)smem;   // 4 waves x 2048 ushorts
#pragma unroll 1
        for (int task = bid; task < 1152; task += GRID)
            attn_body(task, Pl, qt, kt, vtT, Op, Lp);
    }
    grid_bar(&bar[8], GRID);
    {
        unsigned short* As = (unsigned short*)smem;
        unsigned short* Bs = As + 64 * 40;
        float* Linv = (float*)(Bs + 128 * 40);
#pragma unroll 1
        for (int task = bid; task < 576; task += GRID)
            out_body(task, As, Bs, Linv, Op, Lp, w_out, b_out, y);
    }
}

// ---------------------------------------------------------------------------
extern "C" void kernel_launch(void* const* d_in, const int* in_sizes, int n_in,
                              void* d_out, int out_size, void* d_ws, size_t ws_size,
                              hipStream_t stream)
{
    (void)in_sizes; (void)n_in; (void)out_size; (void)ws_size;
    const float* x     = (const float*)d_in[0];
    const float* w_qkv = (const float*)d_in[1];
    const float* w_out = (const float*)d_in[2];
    const float* b_out = (const float*)d_in[3];
    float* y = (float*)d_out;

    unsigned short* qt  = (unsigned short*)d_ws;
    unsigned short* kt  = qt + SEG;
    unsigned short* vtT = kt + SEG;
    unsigned short* Op  = vtT + SEG;                     // PPARTS x SEG bf16
    float* Lp = (float*)(Op + (size_t)PPARTS * SEG);     // PPARTS x LSEG fp32
    unsigned* bar = (unsigned*)(Lp + (size_t)PPARTS * LSEG);  // 2 counters

    // reset barrier counters every launch (capture-legal, stream-ordered)
    hipMemsetAsync(bar, 0, 64, stream);

    fused_kernel<<<dim3(GRID), 256, 0, stream>>>(
        x, w_qkv, w_out, b_out, y, qt, kt, vtT, Op, Lp, bar);
}

// Round 9
// 141.040 us; speedup vs baseline: 3.5450x; 3.5450x over previous
//
#include <hip/hip_runtime.h>
#include <math.h>

#define NB    8
#define CDIM  256
#define NN    2304
#define NH    4
#define DH    32
#define HIDC  128
#define OC3   384
#define SCALE_LOG2E 0.25503524964550864f         // 32^-0.5 * log2(e)
#define SEG   2359296                            // NB*NH*NN*DH
#define LSEG  73728                              // NB*NH*NN
#define PPARTS 4
#define JCHUNK 576                               // NN / PPARTS
#define NITER  18                               // JCHUNK / 32

typedef short  bf16x8 __attribute__((ext_vector_type(8)));
typedef float  f32x4  __attribute__((ext_vector_type(4)));

__device__ __forceinline__ unsigned short f2bf(float f) {
    union { float f; unsigned u; } a; a.f = f;
    unsigned r = a.u + 0x7fffu + ((a.u >> 16) & 1u);   // RNE
    return (unsigned short)(r >> 16);
}

__device__ __forceinline__ unsigned pack_trunc(float lo, float hi) {
    union { float f; unsigned u; } a, b; a.f = lo; b.f = hi;
    return (b.u & 0xFFFF0000u) | (a.u >> 16);          // bf16x2, truncated
}

__device__ __forceinline__ float bflo(unsigned u) {
    union { unsigned u; float f; } c; c.u = u << 16; return c.f;
}
__device__ __forceinline__ float bfhi(unsigned u) {
    union { unsigned u; float f; } c; c.u = u & 0xFFFF0000u; return c.f;
}

// ---------------------------------------------------------------------------
// Kernel 1: QKV projection, 128x128-tile bf16 MFMA GEMM (round-3/5 proven).
// Post-r8 ledger: LDS-free rewrite (r4), o-split (r6), and persistent fusion
// (r7/r8) were all neutral-or-worse for the GEMM-side budget; this form is
// the best measured.  Left untouched.
// ---------------------------------------------------------------------------
__global__ __launch_bounds__(256) void qkv_proj_kernel(
    const float* __restrict__ x, const float* __restrict__ w,
    unsigned short* __restrict__ qt, unsigned short* __restrict__ kt,
    unsigned short* __restrict__ vtT)
{
    __shared__ unsigned short As[128 * 40];
    __shared__ unsigned short Bs[128 * 40];
    // XCD-grouped decode: Lb in [0,432)
    const int Lb   = (int)blockIdx.x;
    const int xcd  = Lb & 7;
    const int t    = Lb >> 3;            // 0..53 (per-XCD sequence)
    const int sel  = t % 3;              // q/k/v varies fastest within XCD
    const int gl   = t / 3;              // 0..17
    const int group = gl * 8 + xcd;      // 0..143
    const int nb   = group % 18;
    const int b    = group / 18;
    const int n0 = nb * 128;
    const int o0 = sel * 128;

    const int tid  = (int)threadIdx.x;
    const int wave = tid >> 6;
    const int lane = tid & 63;
    const int li   = lane & 15;
    const int g    = lane >> 4;
    const int wm = (wave & 1) * 64;
    const int wn = (wave >> 1) * 64;
    const float* xb = x + (size_t)b * CDIM * NN;

    const int aco = (tid & 7) * 4;    // A staging: c offset
    const int aor = tid >> 3;         // A staging: o row 0..31
    const int n4  = (tid & 31) * 4;   // B staging: n base
    const int c4  = (tid >> 5) * 4;   // B staging: c base

    f32x4 acc[4][4];
#pragma unroll
    for (int i = 0; i < 4; ++i)
#pragma unroll
        for (int j = 0; j < 4; ++j) acc[i][j] = (f32x4){0.f, 0.f, 0.f, 0.f};

    float4 wv[4], xv[4];
#pragma unroll
    for (int r = 0; r < 4; ++r)
        wv[r] = *(const float4*)&w[(size_t)(o0 + aor + 32 * r) * CDIM + aco];
#pragma unroll
    for (int dd = 0; dd < 4; ++dd)
        xv[dd] = *(const float4*)&xb[(size_t)(c4 + dd) * NN + n0 + n4];

    for (int k0 = 0; k0 < CDIM; k0 += 32) {
        __syncthreads();
#pragma unroll
        for (int r = 0; r < 4; ++r) {
            uint2 pk;
            pk.x = (unsigned)f2bf(wv[r].x) | ((unsigned)f2bf(wv[r].y) << 16);
            pk.y = (unsigned)f2bf(wv[r].z) | ((unsigned)f2bf(wv[r].w) << 16);
            *(uint2*)&As[(aor + 32 * r) * 40 + aco] = pk;
        }
#pragma unroll
        for (int j = 0; j < 4; ++j) {
            uint2 pk;
            pk.x = (unsigned)f2bf(((const float*)&xv[0])[j])
                 | ((unsigned)f2bf(((const float*)&xv[1])[j]) << 16);
            pk.y = (unsigned)f2bf(((const float*)&xv[2])[j])
                 | ((unsigned)f2bf(((const float*)&xv[3])[j]) << 16);
            *(uint2*)&Bs[(n4 + j) * 40 + c4] = pk;
        }
        __syncthreads();

        // prefetch next K-step (clamped address on last iter; values dead)
        const int kn = (k0 + 32 < CDIM) ? (k0 + 32) : k0;
#pragma unroll
        for (int r = 0; r < 4; ++r)
            wv[r] = *(const float4*)&w[(size_t)(o0 + aor + 32 * r) * CDIM + kn + aco];
#pragma unroll
        for (int dd = 0; dd < 4; ++dd)
            xv[dd] = *(const float4*)&xb[(size_t)(kn + c4 + dd) * NN + n0 + n4];

        bf16x8 af[4], bfr[4];
#pragma unroll
        for (int mt = 0; mt < 4; ++mt)
            af[mt] = *(const bf16x8*)&As[(wm + mt * 16 + li) * 40 + g * 8];
#pragma unroll
        for (int nt = 0; nt < 4; ++nt)
            bfr[nt] = *(const bf16x8*)&Bs[(wn + nt * 16 + li) * 40 + g * 8];
#pragma unroll
        for (int mt = 0; mt < 4; ++mt)
#pragma unroll
            for (int nt = 0; nt < 4; ++nt)
                acc[mt][nt] = __builtin_amdgcn_mfma_f32_16x16x32_bf16(
                    af[mt], bfr[nt], acc[mt][nt], 0, 0, 0);
    }

    if (sel < 2) {
        unsigned short* dst = (sel == 0) ? qt : kt;
        const float mul = (sel == 0) ? SCALE_LOG2E : 1.0f;
#pragma unroll
        for (int mt = 0; mt < 4; ++mt) {
            const int ob = o0 + wm + mt * 16 + g * 4;
            const int d0 = ob & 31;
            const int h  = (ob & 127) >> 5;
            const size_t bh = (size_t)(b * NH + h);
#pragma unroll
            for (int nt = 0; nt < 4; ++nt) {
                const int n = n0 + wn + nt * 16 + li;
                const f32x4 a = acc[mt][nt];
                uint2 pk;
                pk.x = (unsigned)f2bf(a[0] * mul) | ((unsigned)f2bf(a[1] * mul) << 16);
                pk.y = (unsigned)f2bf(a[2] * mul) | ((unsigned)f2bf(a[3] * mul) << 16);
                *(uint2*)&dst[(bh * NN + n) * DH + d0] = pk;
            }
        }
    } else {
#pragma unroll
        for (int mt = 0; mt < 4; ++mt) {
            const int ob = o0 + wm + mt * 16 + g * 4;
            const int d0 = ob & 31;
            const int h  = (ob & 127) >> 5;
            const size_t bh = (size_t)(b * NH + h);
#pragma unroll
            for (int nt = 0; nt < 4; ++nt) {
                const int n = n0 + wn + nt * 16 + li;
                const f32x4 a = acc[mt][nt];
#pragma unroll
                for (int r = 0; r < 4; ++r)
                    vtT[(bh * DH + d0 + r) * (size_t)NN + n] = f2bf(a[r]);
            }
        }
    }
}

// ---------------------------------------------------------------------------
// Kernel 2: MFMA flash attention — round-5 structure (4 Q-frags/wave, 2-deep
// K/V prefetch, LDS P-relayout, O^T epilogue) + THIS round: T5 s_setprio(1)
// around the S-MFMA and PV-MFMA clusters.  attn blocks run unsynchronized at
// different phases, the regime where setprio measured +4-7% (m191); it stays
// OUT of the barrier-lockstep GEMM kernels (m190: neutral/negative there).
// ---------------------------------------------------------------------------
__global__ __launch_bounds__(256) void attn_kernel(
    const unsigned short* __restrict__ qt, const unsigned short* __restrict__ kt,
    const unsigned short* __restrict__ vtT, unsigned short* __restrict__ Op,
    float* __restrict__ Lp)
{
    __shared__ unsigned short Pl[4][4][16 * 32];     // 16 KB
    const int Lb  = (int)blockIdx.x;          // 0..1151
    const int xcd = Lb & 7;
    const int t   = Lb >> 3;                  // 0..143
    const int ib  = t % 9;                    // i-block (256 rows)
    const int grp = (t / 9) * 8 + xcd;        // 0..127, XCD-resident group
    const int bh  = grp >> 2;
    const int part = grp & 3;
    const int jbeg = part * JCHUNK;

    const int tid  = (int)threadIdx.x;
    const int wave = tid >> 6;
    const int lane = tid & 63;
    const int li   = lane & 15;
    const int g    = lane >> 4;
    const int i0   = ib * 256 + wave * 64;

    const unsigned short* qb = qt  + (size_t)bh * NN * DH;
    const unsigned short* kb = kt  + (size_t)bh * NN * DH;
    const unsigned short* vb = vtT + (size_t)bh * DH * NN;

    bf16x8 qfA = *(const bf16x8*)(qb + (size_t)(i0 + li) * DH + g * 8);
    bf16x8 qfB = *(const bf16x8*)(qb + (size_t)(i0 + 16 + li) * DH + g * 8);
    bf16x8 qfC = *(const bf16x8*)(qb + (size_t)(i0 + 32 + li) * DH + g * 8);
    bf16x8 qfD = *(const bf16x8*)(qb + (size_t)(i0 + 48 + li) * DH + g * 8);

    bf16x8 ones;
#pragma unroll
    for (int r = 0; r < 8; ++r) ones[r] = (short)0x3F80;

    f32x4 O0A = {0.f,0.f,0.f,0.f}, O1A = {0.f,0.f,0.f,0.f}, LsA = {0.f,0.f,0.f,0.f};
    f32x4 O0B = {0.f,0.f,0.f,0.f}, O1B = {0.f,0.f,0.f,0.f}, LsB = {0.f,0.f,0.f,0.f};
    f32x4 O0C = {0.f,0.f,0.f,0.f}, O1C = {0.f,0.f,0.f,0.f}, LsC = {0.f,0.f,0.f,0.f};
    f32x4 O0D = {0.f,0.f,0.f,0.f}, O1D = {0.f,0.f,0.f,0.f}, LsD = {0.f,0.f,0.f,0.f};

    unsigned short* plA = &Pl[wave][0][0];
    unsigned short* plB = &Pl[wave][1][0];
    unsigned short* plC = &Pl[wave][2][0];
    unsigned short* plD = &Pl[wave][3][0];
    const int sw  = li & 6;
    const int pw  = li * 32;
    const int wr0 = pw + ((g ^ sw) << 2);          // tile0 chunk g
    const int wr1 = pw + (((4 + g) ^ sw) << 2);    // tile1 chunk 4+g
    const int rdo = pw + (((2 * g) ^ sw) << 2);    // read chunks 2g,2g+1

    const unsigned short* kp0 = kb + (size_t)(jbeg + li) * DH + g * 8;
    const unsigned short* kp1 = kp0 + 16 * DH;
    const unsigned short* vp0 = vb + (size_t)li * NN + jbeg + g * 8;
    const unsigned short* vp1 = vp0 + 16 * NN;

    // 2-deep prefetch: A holds chunk j, B holds chunk j+1
    bf16x8 kf0A = *(const bf16x8*)kp0;
    bf16x8 kf1A = *(const bf16x8*)kp1;
    bf16x8 vf0A = *(const bf16x8*)vp0;
    bf16x8 vf1A = *(const bf16x8*)vp1;
    bf16x8 kf0B = *(const bf16x8*)(kp0 + 32 * DH);
    bf16x8 kf1B = *(const bf16x8*)(kp1 + 32 * DH);
    bf16x8 vf0B = *(const bf16x8*)(vp0 + 32);
    bf16x8 vf1B = *(const bf16x8*)(vp1 + 32);
    kp0 += 64 * DH; kp1 += 64 * DH;   // next chunk to LOAD (j+2)
    vp0 += 64;      vp1 += 64;

#define ATTN_ITER(KF0, KF1, VF0, VF1)                                          \
    do {                                                                       \
        f32x4 z = {0.f, 0.f, 0.f, 0.f};                                        \
        __builtin_amdgcn_s_setprio(1);                                         \
        f32x4 s0A = __builtin_amdgcn_mfma_f32_16x16x32_bf16(KF0, qfA, z, 0, 0, 0); \
        f32x4 s0B = __builtin_amdgcn_mfma_f32_16x16x32_bf16(KF0, qfB, z, 0, 0, 0); \
        f32x4 s0C = __builtin_amdgcn_mfma_f32_16x16x32_bf16(KF0, qfC, z, 0, 0, 0); \
        f32x4 s0D = __builtin_amdgcn_mfma_f32_16x16x32_bf16(KF0, qfD, z, 0, 0, 0); \
        f32x4 s1A = __builtin_amdgcn_mfma_f32_16x16x32_bf16(KF1, qfA, z, 0, 0, 0); \
        f32x4 s1B = __builtin_amdgcn_mfma_f32_16x16x32_bf16(KF1, qfB, z, 0, 0, 0); \
        f32x4 s1C = __builtin_amdgcn_mfma_f32_16x16x32_bf16(KF1, qfC, z, 0, 0, 0); \
        f32x4 s1D = __builtin_amdgcn_mfma_f32_16x16x32_bf16(KF1, qfD, z, 0, 0, 0); \
        __builtin_amdgcn_s_setprio(0);                                         \
        /* KF dead -> reload for iteration it+2 */                             \
        KF0 = *(const bf16x8*)kp0;                                             \
        KF1 = *(const bf16x8*)kp1;                                             \
        kp0 += 32 * DH; kp1 += 32 * DH;                                        \
        float p0A[4], p1A[4], p0B[4], p1B[4];                                  \
        float p0C[4], p1C[4], p0D[4], p1D[4];                                  \
        _Pragma("unroll")                                                      \
        for (int r = 0; r < 4; ++r) {                                          \
            p0A[r] = __builtin_amdgcn_exp2f(s0A[r]);                           \
            p1A[r] = __builtin_amdgcn_exp2f(s1A[r]);                           \
            p0B[r] = __builtin_amdgcn_exp2f(s0B[r]);                           \
            p1B[r] = __builtin_amdgcn_exp2f(s1B[r]);                           \
            p0C[r] = __builtin_amdgcn_exp2f(s0C[r]);                           \
            p1C[r] = __builtin_amdgcn_exp2f(s1C[r]);                           \
            p0D[r] = __builtin_amdgcn_exp2f(s0D[r]);                           \
            p1D[r] = __builtin_amdgcn_exp2f(s1D[r]);                           \
        }                                                                      \
        uint2 wa, wb;                                                          \
        wa.x = pack_trunc(p0A[0], p0A[1]);  wa.y = pack_trunc(p0A[2], p0A[3]); \
        wb.x = pack_trunc(p1A[0], p1A[1]);  wb.y = pack_trunc(p1A[2], p1A[3]); \
        *(uint2*)&plA[wr0] = wa;                                               \
        *(uint2*)&plA[wr1] = wb;                                               \
        wa.x = pack_trunc(p0B[0], p0B[1]);  wa.y = pack_trunc(p0B[2], p0B[3]); \
        wb.x = pack_trunc(p1B[0], p1B[1]);  wb.y = pack_trunc(p1B[2], p1B[3]); \
        *(uint2*)&plB[wr0] = wa;                                               \
        *(uint2*)&plB[wr1] = wb;                                               \
        wa.x = pack_trunc(p0C[0], p0C[1]);  wa.y = pack_trunc(p0C[2], p0C[3]); \
        wb.x = pack_trunc(p1C[0], p1C[1]);  wb.y = pack_trunc(p1C[2], p1C[3]); \
        *(uint2*)&plC[wr0] = wa;                                               \
        *(uint2*)&plC[wr1] = wb;                                               \
        wa.x = pack_trunc(p0D[0], p0D[1]);  wa.y = pack_trunc(p0D[2], p0D[3]); \
        wb.x = pack_trunc(p1D[0], p1D[1]);  wb.y = pack_trunc(p1D[2], p1D[3]); \
        *(uint2*)&plD[wr0] = wa;                                               \
        *(uint2*)&plD[wr1] = wb;                                               \
        bf16x8 pfA = *(const bf16x8*)&plA[rdo];                                \
        bf16x8 pfB = *(const bf16x8*)&plB[rdo];                                \
        bf16x8 pfC = *(const bf16x8*)&plC[rdo];                                \
        bf16x8 pfD = *(const bf16x8*)&plD[rdo];                                \
        __builtin_amdgcn_s_setprio(1);                                         \
        O0A = __builtin_amdgcn_mfma_f32_16x16x32_bf16(VF0,  pfA, O0A, 0, 0, 0); \
        O0B = __builtin_amdgcn_mfma_f32_16x16x32_bf16(VF0,  pfB, O0B, 0, 0, 0); \
        O0C = __builtin_amdgcn_mfma_f32_16x16x32_bf16(VF0,  pfC, O0C, 0, 0, 0); \
        O0D = __builtin_amdgcn_mfma_f32_16x16x32_bf16(VF0,  pfD, O0D, 0, 0, 0); \
        O1A = __builtin_amdgcn_mfma_f32_16x16x32_bf16(VF1,  pfA, O1A, 0, 0, 0); \
        O1B = __builtin_amdgcn_mfma_f32_16x16x32_bf16(VF1,  pfB, O1B, 0, 0, 0); \
        O1C = __builtin_amdgcn_mfma_f32_16x16x32_bf16(VF1,  pfC, O1C, 0, 0, 0); \
        O1D = __builtin_amdgcn_mfma_f32_16x16x32_bf16(VF1,  pfD, O1D, 0, 0, 0); \
        LsA = __builtin_amdgcn_mfma_f32_16x16x32_bf16(ones, pfA, LsA, 0, 0, 0); \
        LsB = __builtin_amdgcn_mfma_f32_16x16x32_bf16(ones, pfB, LsB, 0, 0, 0); \
        LsC = __builtin_amdgcn_mfma_f32_16x16x32_bf16(ones, pfC, LsC, 0, 0, 0); \
        LsD = __builtin_amdgcn_mfma_f32_16x16x32_bf16(ones, pfD, LsD, 0, 0, 0); \
        __builtin_amdgcn_s_setprio(0);                                         \
        /* VF dead -> reload for iteration it+2 */                             \
        VF0 = *(const bf16x8*)vp0;                                             \
        VF1 = *(const bf16x8*)vp1;                                             \
        vp0 += 32; vp1 += 32;                                                  \
    } while (0)

#pragma unroll 1
    for (int it = 0; it < NITER; it += 2) {
        ATTN_ITER(kf0A, kf1A, vf0A, vf1A);
        ATTN_ITER(kf0B, kf1B, vf0B, vf1B);
    }
#undef ATTN_ITER

    // epilogue: Op[part][bh][d][n] bf16 (O^T C-layout: col i=li, row d)
    unsigned short* obA = Op + (size_t)part * SEG + (size_t)bh * DH * NN + i0 + li;
    unsigned short* obB = obA + 16;
    unsigned short* obC = obA + 32;
    unsigned short* obD = obA + 48;
#pragma unroll
    for (int r = 0; r < 4; ++r) {
        obA[(size_t)(4 * g + r)      * NN] = f2bf(O0A[r]);
        obA[(size_t)(16 + 4 * g + r) * NN] = f2bf(O1A[r]);
        obB[(size_t)(4 * g + r)      * NN] = f2bf(O0B[r]);
        obB[(size_t)(16 + 4 * g + r) * NN] = f2bf(O1B[r]);
        obC[(size_t)(4 * g + r)      * NN] = f2bf(O0C[r]);
        obC[(size_t)(16 + 4 * g + r) * NN] = f2bf(O1C[r]);
        obD[(size_t)(4 * g + r)      * NN] = f2bf(O0D[r]);
        obD[(size_t)(16 + 4 * g + r) * NN] = f2bf(O1D[r]);
    }
    if (g == 0) {
        float* lpb = Lp + (size_t)part * LSEG + (size_t)bh * NN + i0 + li;
        lpb[0]  = LsA[0];
        lpb[16] = LsB[0];
        lpb[32] = LsC[0];
        lpb[48] = LsD[0];
    }
}

// ---------------------------------------------------------------------------
// Kernel 3: output projection, 128x128-tile bf16 MFMA GEMM (round-3/5
// proven; left untouched — see kernel-1 comment).
// ---------------------------------------------------------------------------
__global__ __launch_bounds__(256) void out_proj_kernel(
    const unsigned short* __restrict__ Op, const float* __restrict__ Lp,
    const float* __restrict__ w, const float* __restrict__ bias,
    float* __restrict__ y)
{
    __shared__ unsigned short As[128 * 40];
    __shared__ unsigned short Bs[128 * 40];
    __shared__ float Linv[4][128];
    // XCD-grouped decode: Lb in [0,288)
    const int Lb   = (int)blockIdx.x;
    const int xcd  = Lb & 7;
    const int t    = Lb >> 3;            // 0..35
    const int so_  = t % 2;              // o-block varies fastest within XCD
    const int gl   = t / 2;              // 0..17
    const int group = gl * 8 + xcd;      // 0..143
    const int nb   = group % 18;
    const int b    = group / 18;
    const int n0 = nb * 128;
    const int o0 = so_ * 128;

    const int tid  = (int)threadIdx.x;
    const int wave = tid >> 6;
    const int lane = tid & 63;
    const int li   = lane & 15;
    const int g    = lane >> 4;
    const int wm = (wave & 1) * 64;
    const int wn = (wave >> 1) * 64;

    const int aco = (tid & 7) * 4;
    const int aor = tid >> 3;
    const int n4  = (tid & 31) * 4;   // B staging: n base
    const int d4  = (tid >> 5) * 4;   // B staging: d base

    {
        const int h = tid >> 6, nb2 = tid & 63;
#pragma unroll
        for (int half = 0; half < 2; ++half) {
            const int n = nb2 + 64 * half;
            float s = 0.f;
#pragma unroll
            for (int p = 0; p < PPARTS; ++p)
                s += Lp[(size_t)p * LSEG + (size_t)(b * NH + h) * NN + n0 + n];
            Linv[h][n] = 1.0f / s;
        }
    }

    f32x4 acc[4][4];
#pragma unroll
    for (int i = 0; i < 4; ++i)
#pragma unroll
        for (int j = 0; j < 4; ++j) acc[i][j] = (f32x4){0.f, 0.f, 0.f, 0.f};

    float4 wv[4];
    uint2  ov[PPARTS][4];
#pragma unroll
    for (int r = 0; r < 4; ++r)
        wv[r] = *(const float4*)&w[(size_t)(o0 + aor + 32 * r) * HIDC + aco];
    {
        const size_t bh0 = (size_t)(b * NH);
#pragma unroll
        for (int p = 0; p < PPARTS; ++p)
#pragma unroll
            for (int dd = 0; dd < 4; ++dd)
                ov[p][dd] = *(const uint2*)&Op[(size_t)p * SEG
                              + (bh0 * DH + d4 + dd) * (size_t)NN + n0 + n4];
    }

    for (int k0 = 0; k0 < HIDC; k0 += 32) {
        __syncthreads();
#pragma unroll
        for (int r = 0; r < 4; ++r) {
            uint2 pk;
            pk.x = (unsigned)f2bf(wv[r].x) | ((unsigned)f2bf(wv[r].y) << 16);
            pk.y = (unsigned)f2bf(wv[r].z) | ((unsigned)f2bf(wv[r].w) << 16);
            *(uint2*)&As[(aor + 32 * r) * 40 + aco] = pk;
        }
        const int h = k0 >> 5;                      // BK=32 == one head
        {
            float s[4][4];
#pragma unroll
            for (int dd = 0; dd < 4; ++dd)
#pragma unroll
                for (int j = 0; j < 4; ++j) s[dd][j] = 0.f;
#pragma unroll
            for (int p = 0; p < PPARTS; ++p) {
#pragma unroll
                for (int dd = 0; dd < 4; ++dd) {
                    const uint2 u = ov[p][dd];
                    s[dd][0] += bflo(u.x); s[dd][1] += bfhi(u.x);
                    s[dd][2] += bflo(u.y); s[dd][3] += bfhi(u.y);
                }
            }
#pragma unroll
            for (int j = 0; j < 4; ++j) {
                const float lv = Linv[h][n4 + j];
                uint2 pk;
                pk.x = (unsigned)f2bf(s[0][j] * lv) | ((unsigned)f2bf(s[1][j] * lv) << 16);
                pk.y = (unsigned)f2bf(s[2][j] * lv) | ((unsigned)f2bf(s[3][j] * lv) << 16);
                *(uint2*)&Bs[(n4 + j) * 40 + d4] = pk;
            }
        }
        __syncthreads();

        // prefetch next K-step (clamped on last iter; values dead)
        const int kn = (k0 + 32 < HIDC) ? (k0 + 32) : k0;
        const size_t bhn = (size_t)(b * NH + (kn >> 5));
#pragma unroll
        for (int r = 0; r < 4; ++r)
            wv[r] = *(const float4*)&w[(size_t)(o0 + aor + 32 * r) * HIDC + kn + aco];
#pragma unroll
        for (int p = 0; p < PPARTS; ++p)
#pragma unroll
            for (int dd = 0; dd < 4; ++dd)
                ov[p][dd] = *(const uint2*)&Op[(size_t)p * SEG
                              + (bhn * DH + d4 + dd) * (size_t)NN + n0 + n4];

        bf16x8 af[4], bfr[4];
#pragma unroll
        for (int mt = 0; mt < 4; ++mt)
            af[mt] = *(const bf16x8*)&As[(wm + mt * 16 + li) * 40 + g * 8];
#pragma unroll
        for (int nt = 0; nt < 4; ++nt)
            bfr[nt] = *(const bf16x8*)&Bs[(wn + nt * 16 + li) * 40 + g * 8];
#pragma unroll
        for (int mt = 0; mt < 4; ++mt)
#pragma unroll
            for (int nt = 0; nt < 4; ++nt)
                acc[mt][nt] = __builtin_amdgcn_mfma_f32_16x16x32_bf16(
                    af[mt], bfr[nt], acc[mt][nt], 0, 0, 0);
    }

#pragma unroll
    for (int mt = 0; mt < 4; ++mt) {
        const int ob = o0 + wm + mt * 16 + g * 4;
        const float b0 = bias[ob], b1 = bias[ob + 1], b2 = bias[ob + 2], b3 = bias[ob + 3];
#pragma unroll
        for (int nt = 0; nt < 4; ++nt) {
            const int n = n0 + wn + nt * 16 + li;
            const f32x4 a = acc[mt][nt];
            float* yb = y + ((size_t)(b * CDIM + ob)) * NN + n;
            yb[0]              = a[0] + b0;
            yb[(size_t)NN]     = a[1] + b1;
            yb[(size_t)2 * NN] = a[2] + b2;
            yb[(size_t)3 * NN] = a[3] + b3;
        }
    }
}

// ---------------------------------------------------------------------------
extern "C" void kernel_launch(void* const* d_in, const int* in_sizes, int n_in,
                              void* d_out, int out_size, void* d_ws, size_t ws_size,
                              hipStream_t stream)
{
    (void)in_sizes; (void)n_in; (void)out_size; (void)ws_size;
    const float* x     = (const float*)d_in[0];
    const float* w_qkv = (const float*)d_in[1];
    const float* w_out = (const float*)d_in[2];
    const float* b_out = (const float*)d_in[3];
    float* y = (float*)d_out;

    unsigned short* qt  = (unsigned short*)d_ws;
    unsigned short* kt  = qt + SEG;
    unsigned short* vtT = kt + SEG;
    unsigned short* Op  = vtT + SEG;                     // PPARTS x SEG bf16
    float* Lp = (float*)(Op + (size_t)PPARTS * SEG);     // PPARTS x LSEG fp32

    qkv_proj_kernel<<<dim3(432), 256, 0, stream>>>(x, w_qkv, qt, kt, vtT);

    attn_kernel<<<dim3(1152), 256, 0, stream>>>(qt, kt, vtT, Op, Lp);

    out_proj_kernel<<<dim3(288), 256, 0, stream>>>(Op, Lp, w_out, b_out, y);
}

// Round 10
// 138.228 us; speedup vs baseline: 3.6171x; 1.0203x over previous
//
#include <hip/hip_runtime.h>
#include <math.h>

#define NB    8
#define CDIM  256
#define NN    2304
#define NH    4
#define DH    32
#define HIDC  128
#define OC3   384
#define SCALE_LOG2E 0.25503524964550864f         // 32^-0.5 * log2(e)
#define SEG   2359296                            // NB*NH*NN*DH
#define LSEG  73728                              // NB*NH*NN
#define PPARTS 4
#define JCHUNK 576                               // NN / PPARTS
#define NITER  18                               // JCHUNK / 32

typedef short  bf16x8 __attribute__((ext_vector_type(8)));
typedef float  f32x4  __attribute__((ext_vector_type(4)));

__device__ __forceinline__ unsigned short f2bf(float f) {
    union { float f; unsigned u; } a; a.f = f;
    unsigned r = a.u + 0x7fffu + ((a.u >> 16) & 1u);   // RNE
    return (unsigned short)(r >> 16);
}

__device__ __forceinline__ unsigned pack_trunc(float lo, float hi) {
    union { float f; unsigned u; } a, b; a.f = lo; b.f = hi;
    return (b.u & 0xFFFF0000u) | (a.u >> 16);          // bf16x2, truncated
}

__device__ __forceinline__ float bflo(unsigned u) {
    union { unsigned u; float f; } c; c.u = u << 16; return c.f;
}
__device__ __forceinline__ float bfhi(unsigned u) {
    union { unsigned u; float f; } c; c.u = u & 0xFFFF0000u; return c.f;
}

// ---------------------------------------------------------------------------
// Kernel 1: QKV projection, 128x128-tile bf16 MFMA GEMM (r5 base).  THIS
// round: Bs staging was a ~16-way bank conflict (r8's fused profile exposed
// ~5.5M GEMM conflict cycles: 32 lanes write rows 4*(lane&31), stride 320B
// = banks {0,16} only).  Fix: XOR the 16B column-pair index with a 2-bit
// row hash f(m)=(m^(m>>2))&3.  Write key f(tid&31) is j-independent (row>>2
// == tid&31 for j<4); reads recover with f(row>>2).  16B pairs stay intact
// so fragment bytes are identical.  ~16-way -> ~4-way.
// ---------------------------------------------------------------------------
__global__ __launch_bounds__(256) void qkv_proj_kernel(
    const float* __restrict__ x, const float* __restrict__ w,
    unsigned short* __restrict__ qt, unsigned short* __restrict__ kt,
    unsigned short* __restrict__ vtT)
{
    __shared__ unsigned short As[128 * 40];
    __shared__ unsigned short Bs[128 * 40];
    // XCD-grouped decode: Lb in [0,432)
    const int Lb   = (int)blockIdx.x;
    const int xcd  = Lb & 7;
    const int t    = Lb >> 3;            // 0..53 (per-XCD sequence)
    const int sel  = t % 3;              // q/k/v varies fastest within XCD
    const int gl   = t / 3;              // 0..17
    const int group = gl * 8 + xcd;      // 0..143
    const int nb   = group % 18;
    const int b    = group / 18;
    const int n0 = nb * 128;
    const int o0 = sel * 128;

    const int tid  = (int)threadIdx.x;
    const int wave = tid >> 6;
    const int lane = tid & 63;
    const int li   = lane & 15;
    const int g    = lane >> 4;
    const int wm = (wave & 1) * 64;
    const int wn = (wave >> 1) * 64;
    const float* xb = x + (size_t)b * CDIM * NN;

    const int aco = (tid & 7) * 4;    // A staging: c offset
    const int aor = tid >> 3;         // A staging: o row 0..31
    const int n4  = (tid & 31) * 4;   // B staging: n base
    const int c4  = (tid >> 5) * 4;   // B staging: c base (global load)
    // B staging swizzled column (16B-pair XOR with row hash):
    const int l5   = tid & 31;
    const int bkey = (l5 ^ (l5 >> 2)) & 3;
    const int bsw  = ((((tid >> 6) ^ bkey) << 1) | ((tid >> 5) & 1)) << 2;

    f32x4 acc[4][4];
#pragma unroll
    for (int i = 0; i < 4; ++i)
#pragma unroll
        for (int j = 0; j < 4; ++j) acc[i][j] = (f32x4){0.f, 0.f, 0.f, 0.f};

    float4 wv[4], xv[4];
#pragma unroll
    for (int r = 0; r < 4; ++r)
        wv[r] = *(const float4*)&w[(size_t)(o0 + aor + 32 * r) * CDIM + aco];
#pragma unroll
    for (int dd = 0; dd < 4; ++dd)
        xv[dd] = *(const float4*)&xb[(size_t)(c4 + dd) * NN + n0 + n4];

    for (int k0 = 0; k0 < CDIM; k0 += 32) {
        __syncthreads();
#pragma unroll
        for (int r = 0; r < 4; ++r) {
            uint2 pk;
            pk.x = (unsigned)f2bf(wv[r].x) | ((unsigned)f2bf(wv[r].y) << 16);
            pk.y = (unsigned)f2bf(wv[r].z) | ((unsigned)f2bf(wv[r].w) << 16);
            *(uint2*)&As[(aor + 32 * r) * 40 + aco] = pk;
        }
#pragma unroll
        for (int j = 0; j < 4; ++j) {
            uint2 pk;
            pk.x = (unsigned)f2bf(((const float*)&xv[0])[j])
                 | ((unsigned)f2bf(((const float*)&xv[1])[j]) << 16);
            pk.y = (unsigned)f2bf(((const float*)&xv[2])[j])
                 | ((unsigned)f2bf(((const float*)&xv[3])[j]) << 16);
            *(uint2*)&Bs[(n4 + j) * 40 + bsw] = pk;
        }
        __syncthreads();

        // prefetch next K-step (clamped address on last iter; values dead)
        const int kn = (k0 + 32 < CDIM) ? (k0 + 32) : k0;
#pragma unroll
        for (int r = 0; r < 4; ++r)
            wv[r] = *(const float4*)&w[(size_t)(o0 + aor + 32 * r) * CDIM + kn + aco];
#pragma unroll
        for (int dd = 0; dd < 4; ++dd)
            xv[dd] = *(const float4*)&xb[(size_t)(kn + c4 + dd) * NN + n0 + n4];

        bf16x8 af[4], bfr[4];
#pragma unroll
        for (int mt = 0; mt < 4; ++mt)
            af[mt] = *(const bf16x8*)&As[(wm + mt * 16 + li) * 40 + g * 8];
#pragma unroll
        for (int nt = 0; nt < 4; ++nt) {
            const int rr = wn + nt * 16 + li;
            const int rm = rr >> 2;
            bfr[nt] = *(const bf16x8*)&Bs[rr * 40 + ((g ^ ((rm ^ (rm >> 2)) & 3)) << 3)];
        }
#pragma unroll
        for (int mt = 0; mt < 4; ++mt)
#pragma unroll
            for (int nt = 0; nt < 4; ++nt)
                acc[mt][nt] = __builtin_amdgcn_mfma_f32_16x16x32_bf16(
                    af[mt], bfr[nt], acc[mt][nt], 0, 0, 0);
    }

    if (sel < 2) {
        unsigned short* dst = (sel == 0) ? qt : kt;
        const float mul = (sel == 0) ? SCALE_LOG2E : 1.0f;
#pragma unroll
        for (int mt = 0; mt < 4; ++mt) {
            const int ob = o0 + wm + mt * 16 + g * 4;
            const int d0 = ob & 31;
            const int h  = (ob & 127) >> 5;
            const size_t bh = (size_t)(b * NH + h);
#pragma unroll
            for (int nt = 0; nt < 4; ++nt) {
                const int n = n0 + wn + nt * 16 + li;
                const f32x4 a = acc[mt][nt];
                uint2 pk;
                pk.x = (unsigned)f2bf(a[0] * mul) | ((unsigned)f2bf(a[1] * mul) << 16);
                pk.y = (unsigned)f2bf(a[2] * mul) | ((unsigned)f2bf(a[3] * mul) << 16);
                *(uint2*)&dst[(bh * NN + n) * DH + d0] = pk;
            }
        }
    } else {
#pragma unroll
        for (int mt = 0; mt < 4; ++mt) {
            const int ob = o0 + wm + mt * 16 + g * 4;
            const int d0 = ob & 31;
            const int h  = (ob & 127) >> 5;
            const size_t bh = (size_t)(b * NH + h);
#pragma unroll
            for (int nt = 0; nt < 4; ++nt) {
                const int n = n0 + wn + nt * 16 + li;
                const f32x4 a = acc[mt][nt];
#pragma unroll
                for (int r = 0; r < 4; ++r)
                    vtT[(bh * DH + d0 + r) * (size_t)NN + n] = f2bf(a[r]);
            }
        }
    }
}

// ---------------------------------------------------------------------------
// Kernel 2: MFMA flash attention — round-5 winner, exact (4 Q-frags/wave,
// 2-deep K/V prefetch, LDS P-relayout, O^T epilogue).  setprio reverted:
// r9 showed it neutral within the +/-2.5us run-noise band.
// ---------------------------------------------------------------------------
__global__ __launch_bounds__(256) void attn_kernel(
    const unsigned short* __restrict__ qt, const unsigned short* __restrict__ kt,
    const unsigned short* __restrict__ vtT, unsigned short* __restrict__ Op,
    float* __restrict__ Lp)
{
    __shared__ unsigned short Pl[4][4][16 * 32];     // 16 KB
    const int Lb  = (int)blockIdx.x;          // 0..1151
    const int xcd = Lb & 7;
    const int t   = Lb >> 3;                  // 0..143
    const int ib  = t % 9;                    // i-block (256 rows)
    const int grp = (t / 9) * 8 + xcd;        // 0..127, XCD-resident group
    const int bh  = grp >> 2;
    const int part = grp & 3;
    const int jbeg = part * JCHUNK;

    const int tid  = (int)threadIdx.x;
    const int wave = tid >> 6;
    const int lane = tid & 63;
    const int li   = lane & 15;
    const int g    = lane >> 4;
    const int i0   = ib * 256 + wave * 64;

    const unsigned short* qb = qt  + (size_t)bh * NN * DH;
    const unsigned short* kb = kt  + (size_t)bh * NN * DH;
    const unsigned short* vb = vtT + (size_t)bh * DH * NN;

    bf16x8 qfA = *(const bf16x8*)(qb + (size_t)(i0 + li) * DH + g * 8);
    bf16x8 qfB = *(const bf16x8*)(qb + (size_t)(i0 + 16 + li) * DH + g * 8);
    bf16x8 qfC = *(const bf16x8*)(qb + (size_t)(i0 + 32 + li) * DH + g * 8);
    bf16x8 qfD = *(const bf16x8*)(qb + (size_t)(i0 + 48 + li) * DH + g * 8);

    bf16x8 ones;
#pragma unroll
    for (int r = 0; r < 8; ++r) ones[r] = (short)0x3F80;

    f32x4 O0A = {0.f,0.f,0.f,0.f}, O1A = {0.f,0.f,0.f,0.f}, LsA = {0.f,0.f,0.f,0.f};
    f32x4 O0B = {0.f,0.f,0.f,0.f}, O1B = {0.f,0.f,0.f,0.f}, LsB = {0.f,0.f,0.f,0.f};
    f32x4 O0C = {0.f,0.f,0.f,0.f}, O1C = {0.f,0.f,0.f,0.f}, LsC = {0.f,0.f,0.f,0.f};
    f32x4 O0D = {0.f,0.f,0.f,0.f}, O1D = {0.f,0.f,0.f,0.f}, LsD = {0.f,0.f,0.f,0.f};

    unsigned short* plA = &Pl[wave][0][0];
    unsigned short* plB = &Pl[wave][1][0];
    unsigned short* plC = &Pl[wave][2][0];
    unsigned short* plD = &Pl[wave][3][0];
    const int sw  = li & 6;
    const int pw  = li * 32;
    const int wr0 = pw + ((g ^ sw) << 2);          // tile0 chunk g
    const int wr1 = pw + (((4 + g) ^ sw) << 2);    // tile1 chunk 4+g
    const int rdo = pw + (((2 * g) ^ sw) << 2);    // read chunks 2g,2g+1

    const unsigned short* kp0 = kb + (size_t)(jbeg + li) * DH + g * 8;
    const unsigned short* kp1 = kp0 + 16 * DH;
    const unsigned short* vp0 = vb + (size_t)li * NN + jbeg + g * 8;
    const unsigned short* vp1 = vp0 + 16 * NN;

    // 2-deep prefetch: A holds chunk j, B holds chunk j+1
    bf16x8 kf0A = *(const bf16x8*)kp0;
    bf16x8 kf1A = *(const bf16x8*)kp1;
    bf16x8 vf0A = *(const bf16x8*)vp0;
    bf16x8 vf1A = *(const bf16x8*)vp1;
    bf16x8 kf0B = *(const bf16x8*)(kp0 + 32 * DH);
    bf16x8 kf1B = *(const bf16x8*)(kp1 + 32 * DH);
    bf16x8 vf0B = *(const bf16x8*)(vp0 + 32);
    bf16x8 vf1B = *(const bf16x8*)(vp1 + 32);
    kp0 += 64 * DH; kp1 += 64 * DH;   // next chunk to LOAD (j+2)
    vp0 += 64;      vp1 += 64;

#define ATTN_ITER(KF0, KF1, VF0, VF1)                                          \
    do {                                                                       \
        f32x4 z = {0.f, 0.f, 0.f, 0.f};                                        \
        f32x4 s0A = __builtin_amdgcn_mfma_f32_16x16x32_bf16(KF0, qfA, z, 0, 0, 0); \
        f32x4 s0B = __builtin_amdgcn_mfma_f32_16x16x32_bf16(KF0, qfB, z, 0, 0, 0); \
        f32x4 s0C = __builtin_amdgcn_mfma_f32_16x16x32_bf16(KF0, qfC, z, 0, 0, 0); \
        f32x4 s0D = __builtin_amdgcn_mfma_f32_16x16x32_bf16(KF0, qfD, z, 0, 0, 0); \
        f32x4 s1A = __builtin_amdgcn_mfma_f32_16x16x32_bf16(KF1, qfA, z, 0, 0, 0); \
        f32x4 s1B = __builtin_amdgcn_mfma_f32_16x16x32_bf16(KF1, qfB, z, 0, 0, 0); \
        f32x4 s1C = __builtin_amdgcn_mfma_f32_16x16x32_bf16(KF1, qfC, z, 0, 0, 0); \
        f32x4 s1D = __builtin_amdgcn_mfma_f32_16x16x32_bf16(KF1, qfD, z, 0, 0, 0); \
        /* KF dead -> reload for iteration it+2 */                             \
        KF0 = *(const bf16x8*)kp0;                                             \
        KF1 = *(const bf16x8*)kp1;                                             \
        kp0 += 32 * DH; kp1 += 32 * DH;                                        \
        float p0A[4], p1A[4], p0B[4], p1B[4];                                  \
        float p0C[4], p1C[4], p0D[4], p1D[4];                                  \
        _Pragma("unroll")                                                      \
        for (int r = 0; r < 4; ++r) {                                          \
            p0A[r] = __builtin_amdgcn_exp2f(s0A[r]);                           \
            p1A[r] = __builtin_amdgcn_exp2f(s1A[r]);                           \
            p0B[r] = __builtin_amdgcn_exp2f(s0B[r]);                           \
            p1B[r] = __builtin_amdgcn_exp2f(s1B[r]);                           \
            p0C[r] = __builtin_amdgcn_exp2f(s0C[r]);                           \
            p1C[r] = __builtin_amdgcn_exp2f(s1C[r]);                           \
            p0D[r] = __builtin_amdgcn_exp2f(s0D[r]);                           \
            p1D[r] = __builtin_amdgcn_exp2f(s1D[r]);                           \
        }                                                                      \
        uint2 wa, wb;                                                          \
        wa.x = pack_trunc(p0A[0], p0A[1]);  wa.y = pack_trunc(p0A[2], p0A[3]); \
        wb.x = pack_trunc(p1A[0], p1A[1]);  wb.y = pack_trunc(p1A[2], p1A[3]); \
        *(uint2*)&plA[wr0] = wa;                                               \
        *(uint2*)&plA[wr1] = wb;                                               \
        wa.x = pack_trunc(p0B[0], p0B[1]);  wa.y = pack_trunc(p0B[2], p0B[3]); \
        wb.x = pack_trunc(p1B[0], p1B[1]);  wb.y = pack_trunc(p1B[2], p1B[3]); \
        *(uint2*)&plB[wr0] = wa;                                               \
        *(uint2*)&plB[wr1] = wb;                                               \
        wa.x = pack_trunc(p0C[0], p0C[1]);  wa.y = pack_trunc(p0C[2], p0C[3]); \
        wb.x = pack_trunc(p1C[0], p1C[1]);  wb.y = pack_trunc(p1C[2], p1C[3]); \
        *(uint2*)&plC[wr0] = wa;                                               \
        *(uint2*)&plC[wr1] = wb;                                               \
        wa.x = pack_trunc(p0D[0], p0D[1]);  wa.y = pack_trunc(p0D[2], p0D[3]); \
        wb.x = pack_trunc(p1D[0], p1D[1]);  wb.y = pack_trunc(p1D[2], p1D[3]); \
        *(uint2*)&plD[wr0] = wa;                                               \
        *(uint2*)&plD[wr1] = wb;                                               \
        bf16x8 pfA = *(const bf16x8*)&plA[rdo];                                \
        bf16x8 pfB = *(const bf16x8*)&plB[rdo];                                \
        bf16x8 pfC = *(const bf16x8*)&plC[rdo];                                \
        bf16x8 pfD = *(const bf16x8*)&plD[rdo];                                \
        O0A = __builtin_amdgcn_mfma_f32_16x16x32_bf16(VF0,  pfA, O0A, 0, 0, 0); \
        O0B = __builtin_amdgcn_mfma_f32_16x16x32_bf16(VF0,  pfB, O0B, 0, 0, 0); \
        O0C = __builtin_amdgcn_mfma_f32_16x16x32_bf16(VF0,  pfC, O0C, 0, 0, 0); \
        O0D = __builtin_amdgcn_mfma_f32_16x16x32_bf16(VF0,  pfD, O0D, 0, 0, 0); \
        O1A = __builtin_amdgcn_mfma_f32_16x16x32_bf16(VF1,  pfA, O1A, 0, 0, 0); \
        O1B = __builtin_amdgcn_mfma_f32_16x16x32_bf16(VF1,  pfB, O1B, 0, 0, 0); \
        O1C = __builtin_amdgcn_mfma_f32_16x16x32_bf16(VF1,  pfC, O1C, 0, 0, 0); \
        O1D = __builtin_amdgcn_mfma_f32_16x16x32_bf16(VF1,  pfD, O1D, 0, 0, 0); \
        LsA = __builtin_amdgcn_mfma_f32_16x16x32_bf16(ones, pfA, LsA, 0, 0, 0); \
        LsB = __builtin_amdgcn_mfma_f32_16x16x32_bf16(ones, pfB, LsB, 0, 0, 0); \
        LsC = __builtin_amdgcn_mfma_f32_16x16x32_bf16(ones, pfC, LsC, 0, 0, 0); \
        LsD = __builtin_amdgcn_mfma_f32_16x16x32_bf16(ones, pfD, LsD, 0, 0, 0); \
        /* VF dead -> reload for iteration it+2 */                             \
        VF0 = *(const bf16x8*)vp0;                                             \
        VF1 = *(const bf16x8*)vp1;                                             \
        vp0 += 32; vp1 += 32;                                                  \
    } while (0)

#pragma unroll 1
    for (int it = 0; it < NITER; it += 2) {
        ATTN_ITER(kf0A, kf1A, vf0A, vf1A);
        ATTN_ITER(kf0B, kf1B, vf0B, vf1B);
    }
#undef ATTN_ITER

    // epilogue: Op[part][bh][d][n] bf16 (O^T C-layout: col i=li, row d)
    unsigned short* obA = Op + (size_t)part * SEG + (size_t)bh * DH * NN + i0 + li;
    unsigned short* obB = obA + 16;
    unsigned short* obC = obA + 32;
    unsigned short* obD = obA + 48;
#pragma unroll
    for (int r = 0; r < 4; ++r) {
        obA[(size_t)(4 * g + r)      * NN] = f2bf(O0A[r]);
        obA[(size_t)(16 + 4 * g + r) * NN] = f2bf(O1A[r]);
        obB[(size_t)(4 * g + r)      * NN] = f2bf(O0B[r]);
        obB[(size_t)(16 + 4 * g + r) * NN] = f2bf(O1B[r]);
        obC[(size_t)(4 * g + r)      * NN] = f2bf(O0C[r]);
        obC[(size_t)(16 + 4 * g + r) * NN] = f2bf(O1C[r]);
        obD[(size_t)(4 * g + r)      * NN] = f2bf(O0D[r]);
        obD[(size_t)(16 + 4 * g + r) * NN] = f2bf(O1D[r]);
    }
    if (g == 0) {
        float* lpb = Lp + (size_t)part * LSEG + (size_t)bh * NN + i0 + li;
        lpb[0]  = LsA[0];
        lpb[16] = LsB[0];
        lpb[32] = LsC[0];
        lpb[48] = LsD[0];
    }
}

// ---------------------------------------------------------------------------
// Kernel 3: output projection, 128x128-tile bf16 MFMA GEMM (r5 base) with
// the same Bs bank-conflict swizzle as kernel 1 (identical write pattern,
// identical fix).
// ---------------------------------------------------------------------------
__global__ __launch_bounds__(256) void out_proj_kernel(
    const unsigned short* __restrict__ Op, const float* __restrict__ Lp,
    const float* __restrict__ w, const float* __restrict__ bias,
    float* __restrict__ y)
{
    __shared__ unsigned short As[128 * 40];
    __shared__ unsigned short Bs[128 * 40];
    __shared__ float Linv[4][128];
    // XCD-grouped decode: Lb in [0,288)
    const int Lb   = (int)blockIdx.x;
    const int xcd  = Lb & 7;
    const int t    = Lb >> 3;            // 0..35
    const int so_  = t % 2;              // o-block varies fastest within XCD
    const int gl   = t / 2;              // 0..17
    const int group = gl * 8 + xcd;      // 0..143
    const int nb   = group % 18;
    const int b    = group / 18;
    const int n0 = nb * 128;
    const int o0 = so_ * 128;

    const int tid  = (int)threadIdx.x;
    const int wave = tid >> 6;
    const int lane = tid & 63;
    const int li   = lane & 15;
    const int g    = lane >> 4;
    const int wm = (wave & 1) * 64;
    const int wn = (wave >> 1) * 64;

    const int aco = (tid & 7) * 4;
    const int aor = tid >> 3;
    const int n4  = (tid & 31) * 4;   // B staging: n base
    const int d4  = (tid >> 5) * 4;   // B staging: d base (global load)
    const int l5   = tid & 31;
    const int bkey = (l5 ^ (l5 >> 2)) & 3;
    const int bsw  = ((((tid >> 6) ^ bkey) << 1) | ((tid >> 5) & 1)) << 2;

    {
        const int h = tid >> 6, nb2 = tid & 63;
#pragma unroll
        for (int half = 0; half < 2; ++half) {
            const int n = nb2 + 64 * half;
            float s = 0.f;
#pragma unroll
            for (int p = 0; p < PPARTS; ++p)
                s += Lp[(size_t)p * LSEG + (size_t)(b * NH + h) * NN + n0 + n];
            Linv[h][n] = 1.0f / s;
        }
    }

    f32x4 acc[4][4];
#pragma unroll
    for (int i = 0; i < 4; ++i)
#pragma unroll
        for (int j = 0; j < 4; ++j) acc[i][j] = (f32x4){0.f, 0.f, 0.f, 0.f};

    float4 wv[4];
    uint2  ov[PPARTS][4];
#pragma unroll
    for (int r = 0; r < 4; ++r)
        wv[r] = *(const float4*)&w[(size_t)(o0 + aor + 32 * r) * HIDC + aco];
    {
        const size_t bh0 = (size_t)(b * NH);
#pragma unroll
        for (int p = 0; p < PPARTS; ++p)
#pragma unroll
            for (int dd = 0; dd < 4; ++dd)
                ov[p][dd] = *(const uint2*)&Op[(size_t)p * SEG
                              + (bh0 * DH + d4 + dd) * (size_t)NN + n0 + n4];
    }

    for (int k0 = 0; k0 < HIDC; k0 += 32) {
        __syncthreads();
#pragma unroll
        for (int r = 0; r < 4; ++r) {
            uint2 pk;
            pk.x = (unsigned)f2bf(wv[r].x) | ((unsigned)f2bf(wv[r].y) << 16);
            pk.y = (unsigned)f2bf(wv[r].z) | ((unsigned)f2bf(wv[r].w) << 16);
            *(uint2*)&As[(aor + 32 * r) * 40 + aco] = pk;
        }
        const int h = k0 >> 5;                      // BK=32 == one head
        {
            float s[4][4];
#pragma unroll
            for (int dd = 0; dd < 4; ++dd)
#pragma unroll
                for (int j = 0; j < 4; ++j) s[dd][j] = 0.f;
#pragma unroll
            for (int p = 0; p < PPARTS; ++p) {
#pragma unroll
                for (int dd = 0; dd < 4; ++dd) {
                    const uint2 u = ov[p][dd];
                    s[dd][0] += bflo(u.x); s[dd][1] += bfhi(u.x);
                    s[dd][2] += bflo(u.y); s[dd][3] += bfhi(u.y);
                }
            }
#pragma unroll
            for (int j = 0; j < 4; ++j) {
                const float lv = Linv[h][n4 + j];
                uint2 pk;
                pk.x = (unsigned)f2bf(s[0][j] * lv) | ((unsigned)f2bf(s[1][j] * lv) << 16);
                pk.y = (unsigned)f2bf(s[2][j] * lv) | ((unsigned)f2bf(s[3][j] * lv) << 16);
                *(uint2*)&Bs[(n4 + j) * 40 + bsw] = pk;
            }
        }
        __syncthreads();

        // prefetch next K-step (clamped on last iter; values dead)
        const int kn = (k0 + 32 < HIDC) ? (k0 + 32) : k0;
        const size_t bhn = (size_t)(b * NH + (kn >> 5));
#pragma unroll
        for (int r = 0; r < 4; ++r)
            wv[r] = *(const float4*)&w[(size_t)(o0 + aor + 32 * r) * HIDC + kn + aco];
#pragma unroll
        for (int p = 0; p < PPARTS; ++p)
#pragma unroll
            for (int dd = 0; dd < 4; ++dd)
                ov[p][dd] = *(const uint2*)&Op[(size_t)p * SEG
                              + (bhn * DH + d4 + dd) * (size_t)NN + n0 + n4];

        bf16x8 af[4], bfr[4];
#pragma unroll
        for (int mt = 0; mt < 4; ++mt)
            af[mt] = *(const bf16x8*)&As[(wm + mt * 16 + li) * 40 + g * 8];
#pragma unroll
        for (int nt = 0; nt < 4; ++nt) {
            const int rr = wn + nt * 16 + li;
            const int rm = rr >> 2;
            bfr[nt] = *(const bf16x8*)&Bs[rr * 40 + ((g ^ ((rm ^ (rm >> 2)) & 3)) << 3)];
        }
#pragma unroll
        for (int mt = 0; mt < 4; ++mt)
#pragma unroll
            for (int nt = 0; nt < 4; ++nt)
                acc[mt][nt] = __builtin_amdgcn_mfma_f32_16x16x32_bf16(
                    af[mt], bfr[nt], acc[mt][nt], 0, 0, 0);
    }

#pragma unroll
    for (int mt = 0; mt < 4; ++mt) {
        const int ob = o0 + wm + mt * 16 + g * 4;
        const float b0 = bias[ob], b1 = bias[ob + 1], b2 = bias[ob + 2], b3 = bias[ob + 3];
#pragma unroll
        for (int nt = 0; nt < 4; ++nt) {
            const int n = n0 + wn + nt * 16 + li;
            const f32x4 a = acc[mt][nt];
            float* yb = y + ((size_t)(b * CDIM + ob)) * NN + n;
            yb[0]              = a[0] + b0;
            yb[(size_t)NN]     = a[1] + b1;
            yb[(size_t)2 * NN] = a[2] + b2;
            yb[(size_t)3 * NN] = a[3] + b3;
        }
    }
}

// ---------------------------------------------------------------------------
extern "C" void kernel_launch(void* const* d_in, const int* in_sizes, int n_in,
                              void* d_out, int out_size, void* d_ws, size_t ws_size,
                              hipStream_t stream)
{
    (void)in_sizes; (void)n_in; (void)out_size; (void)ws_size;
    const float* x     = (const float*)d_in[0];
    const float* w_qkv = (const float*)d_in[1];
    const float* w_out = (const float*)d_in[2];
    const float* b_out = (const float*)d_in[3];
    float* y = (float*)d_out;

    unsigned short* qt  = (unsigned short*)d_ws;
    unsigned short* kt  = qt + SEG;
    unsigned short* vtT = kt + SEG;
    unsigned short* Op  = vtT + SEG;                     // PPARTS x SEG bf16
    float* Lp = (float*)(Op + (size_t)PPARTS * SEG);     // PPARTS x LSEG fp32

    qkv_proj_kernel<<<dim3(432), 256, 0, stream>>>(x, w_qkv, qt, kt, vtT);

    attn_kernel<<<dim3(1152), 256, 0, stream>>>(qt, kt, vtT, Op, Lp);

    out_proj_kernel<<<dim3(288), 256, 0, stream>>>(Op, Lp, w_out, b_out, y);
}

// Round 11
// 135.144 us; speedup vs baseline: 3.6997x; 1.0228x over previous
//
#include <hip/hip_runtime.h>
#include <math.h>

#define NB    8
#define CDIM  256
#define NN    2304
#define NH    4
#define DH    32
#define HIDC  128
#define OC3   384
#define SCALE_LOG2E 0.25503524964550864f         // 32^-0.5 * log2(e)
#define SEG   2359296                            // NB*NH*NN*DH
#define LSEG  73728                              // NB*NH*NN
#define PPARTS 4
#define JCHUNK 576                               // NN / PPARTS
#define NITER  18                               // JCHUNK / 32
#define NFRAG 6                                  // Q-fragments per wave (96 rows)

typedef short  bf16x8 __attribute__((ext_vector_type(8)));
typedef float  f32x4  __attribute__((ext_vector_type(4)));

__device__ __forceinline__ unsigned short f2bf(float f) {
    union { float f; unsigned u; } a; a.f = f;
    unsigned r = a.u + 0x7fffu + ((a.u >> 16) & 1u);   // RNE
    return (unsigned short)(r >> 16);
}

__device__ __forceinline__ unsigned pack_trunc(float lo, float hi) {
    union { float f; unsigned u; } a, b; a.f = lo; b.f = hi;
    return (b.u & 0xFFFF0000u) | (a.u >> 16);          // bf16x2, truncated
}

__device__ __forceinline__ float bflo(unsigned u) {
    union { unsigned u; float f; } c; c.u = u << 16; return c.f;
}
__device__ __forceinline__ float bfhi(unsigned u) {
    union { unsigned u; float f; } c; c.u = u & 0xFFFF0000u; return c.f;
}

// ---------------------------------------------------------------------------
// Kernel 1: QKV projection, 128x128-tile bf16 MFMA GEMM (r10 winner: Bs
// bank-conflict swizzle — 16B-pair column XOR'd with row hash).  Untouched.
// ---------------------------------------------------------------------------
__global__ __launch_bounds__(256) void qkv_proj_kernel(
    const float* __restrict__ x, const float* __restrict__ w,
    unsigned short* __restrict__ qt, unsigned short* __restrict__ kt,
    unsigned short* __restrict__ vtT)
{
    __shared__ unsigned short As[128 * 40];
    __shared__ unsigned short Bs[128 * 40];
    // XCD-grouped decode: Lb in [0,432)
    const int Lb   = (int)blockIdx.x;
    const int xcd  = Lb & 7;
    const int t    = Lb >> 3;            // 0..53 (per-XCD sequence)
    const int sel  = t % 3;              // q/k/v varies fastest within XCD
    const int gl   = t / 3;              // 0..17
    const int group = gl * 8 + xcd;      // 0..143
    const int nb   = group % 18;
    const int b    = group / 18;
    const int n0 = nb * 128;
    const int o0 = sel * 128;

    const int tid  = (int)threadIdx.x;
    const int wave = tid >> 6;
    const int lane = tid & 63;
    const int li   = lane & 15;
    const int g    = lane >> 4;
    const int wm = (wave & 1) * 64;
    const int wn = (wave >> 1) * 64;
    const float* xb = x + (size_t)b * CDIM * NN;

    const int aco = (tid & 7) * 4;    // A staging: c offset
    const int aor = tid >> 3;         // A staging: o row 0..31
    const int n4  = (tid & 31) * 4;   // B staging: n base
    const int c4  = (tid >> 5) * 4;   // B staging: c base (global load)
    // B staging swizzled column (16B-pair XOR with row hash):
    const int l5   = tid & 31;
    const int bkey = (l5 ^ (l5 >> 2)) & 3;
    const int bsw  = ((((tid >> 6) ^ bkey) << 1) | ((tid >> 5) & 1)) << 2;

    f32x4 acc[4][4];
#pragma unroll
    for (int i = 0; i < 4; ++i)
#pragma unroll
        for (int j = 0; j < 4; ++j) acc[i][j] = (f32x4){0.f, 0.f, 0.f, 0.f};

    float4 wv[4], xv[4];
#pragma unroll
    for (int r = 0; r < 4; ++r)
        wv[r] = *(const float4*)&w[(size_t)(o0 + aor + 32 * r) * CDIM + aco];
#pragma unroll
    for (int dd = 0; dd < 4; ++dd)
        xv[dd] = *(const float4*)&xb[(size_t)(c4 + dd) * NN + n0 + n4];

    for (int k0 = 0; k0 < CDIM; k0 += 32) {
        __syncthreads();
#pragma unroll
        for (int r = 0; r < 4; ++r) {
            uint2 pk;
            pk.x = (unsigned)f2bf(wv[r].x) | ((unsigned)f2bf(wv[r].y) << 16);
            pk.y = (unsigned)f2bf(wv[r].z) | ((unsigned)f2bf(wv[r].w) << 16);
            *(uint2*)&As[(aor + 32 * r) * 40 + aco] = pk;
        }
#pragma unroll
        for (int j = 0; j < 4; ++j) {
            uint2 pk;
            pk.x = (unsigned)f2bf(((const float*)&xv[0])[j])
                 | ((unsigned)f2bf(((const float*)&xv[1])[j]) << 16);
            pk.y = (unsigned)f2bf(((const float*)&xv[2])[j])
                 | ((unsigned)f2bf(((const float*)&xv[3])[j]) << 16);
            *(uint2*)&Bs[(n4 + j) * 40 + bsw] = pk;
        }
        __syncthreads();

        // prefetch next K-step (clamped address on last iter; values dead)
        const int kn = (k0 + 32 < CDIM) ? (k0 + 32) : k0;
#pragma unroll
        for (int r = 0; r < 4; ++r)
            wv[r] = *(const float4*)&w[(size_t)(o0 + aor + 32 * r) * CDIM + kn + aco];
#pragma unroll
        for (int dd = 0; dd < 4; ++dd)
            xv[dd] = *(const float4*)&xb[(size_t)(kn + c4 + dd) * NN + n0 + n4];

        bf16x8 af[4], bfr[4];
#pragma unroll
        for (int mt = 0; mt < 4; ++mt)
            af[mt] = *(const bf16x8*)&As[(wm + mt * 16 + li) * 40 + g * 8];
#pragma unroll
        for (int nt = 0; nt < 4; ++nt) {
            const int rr = wn + nt * 16 + li;
            const int rm = rr >> 2;
            bfr[nt] = *(const bf16x8*)&Bs[rr * 40 + ((g ^ ((rm ^ (rm >> 2)) & 3)) << 3)];
        }
#pragma unroll
        for (int mt = 0; mt < 4; ++mt)
#pragma unroll
            for (int nt = 0; nt < 4; ++nt)
                acc[mt][nt] = __builtin_amdgcn_mfma_f32_16x16x32_bf16(
                    af[mt], bfr[nt], acc[mt][nt], 0, 0, 0);
    }

    if (sel < 2) {
        unsigned short* dst = (sel == 0) ? qt : kt;
        const float mul = (sel == 0) ? SCALE_LOG2E : 1.0f;
#pragma unroll
        for (int mt = 0; mt < 4; ++mt) {
            const int ob = o0 + wm + mt * 16 + g * 4;
            const int d0 = ob & 31;
            const int h  = (ob & 127) >> 5;
            const size_t bh = (size_t)(b * NH + h);
#pragma unroll
            for (int nt = 0; nt < 4; ++nt) {
                const int n = n0 + wn + nt * 16 + li;
                const f32x4 a = acc[mt][nt];
                uint2 pk;
                pk.x = (unsigned)f2bf(a[0] * mul) | ((unsigned)f2bf(a[1] * mul) << 16);
                pk.y = (unsigned)f2bf(a[2] * mul) | ((unsigned)f2bf(a[3] * mul) << 16);
                *(uint2*)&dst[(bh * NN + n) * DH + d0] = pk;
            }
        }
    } else {
#pragma unroll
        for (int mt = 0; mt < 4; ++mt) {
            const int ob = o0 + wm + mt * 16 + g * 4;
            const int d0 = ob & 31;
            const int h  = (ob & 127) >> 5;
            const size_t bh = (size_t)(b * NH + h);
#pragma unroll
            for (int nt = 0; nt < 4; ++nt) {
                const int n = n0 + wn + nt * 16 + li;
                const f32x4 a = acc[mt][nt];
#pragma unroll
                for (int r = 0; r < 4; ++r)
                    vtT[(bh * DH + d0 + r) * (size_t)NN + n] = f2bf(a[r]);
            }
        }
    }
}

// ---------------------------------------------------------------------------
// Kernel 2: MFMA flash attention — THIS round: 6 Q-fragments/wave (was 4),
// repeating the one proven lever (r3: 2->4 frags = +36%).  96 rows/wave,
// 384/block, exact fit 2304 = 6 i-blocks.  Grid 1152 -> 768.  K/V prefetch
// dropped to 1-deep to hold VGPR ~<200 (r5 measured 2-deep worth only
// ~2.7us at 4-frag; the 1.5x-longer iteration restores the same absolute
// load-to-use distance).  LDS P-relayout and O^T epilogue unchanged.
// ---------------------------------------------------------------------------
__global__ __launch_bounds__(256) void attn_kernel(
    const unsigned short* __restrict__ qt, const unsigned short* __restrict__ kt,
    const unsigned short* __restrict__ vtT, unsigned short* __restrict__ Op,
    float* __restrict__ Lp)
{
    __shared__ unsigned short Pl[4][NFRAG][512];     // 24 KB
    const int Lb  = (int)blockIdx.x;          // 0..767
    const int xcd = Lb & 7;
    const int t   = Lb >> 3;                  // 0..95
    const int ib  = t % NFRAG;                // i-block (384 rows)
    const int grp = (t / NFRAG) * 8 + xcd;    // 0..127, XCD-resident group
    const int bh  = grp >> 2;
    const int part = grp & 3;
    const int jbeg = part * JCHUNK;

    const int tid  = (int)threadIdx.x;
    const int wave = tid >> 6;
    const int lane = tid & 63;
    const int li   = lane & 15;
    const int g    = lane >> 4;
    const int i0   = ib * 384 + wave * 96;

    const unsigned short* qb = qt  + (size_t)bh * NN * DH;
    const unsigned short* kb = kt  + (size_t)bh * NN * DH;
    const unsigned short* vb = vtT + (size_t)bh * DH * NN;

    bf16x8 qf[NFRAG];
#pragma unroll
    for (int f = 0; f < NFRAG; ++f)
        qf[f] = *(const bf16x8*)(qb + (size_t)(i0 + f * 16 + li) * DH + g * 8);

    bf16x8 ones;
#pragma unroll
    for (int r = 0; r < 8; ++r) ones[r] = (short)0x3F80;

    f32x4 O0[NFRAG], O1[NFRAG], Ls[NFRAG];
#pragma unroll
    for (int f = 0; f < NFRAG; ++f) {
        O0[f] = (f32x4){0.f, 0.f, 0.f, 0.f};
        O1[f] = (f32x4){0.f, 0.f, 0.f, 0.f};
        Ls[f] = (f32x4){0.f, 0.f, 0.f, 0.f};
    }

    const int sw  = li & 6;
    const int pw  = li * 32;
    const int wr0 = pw + ((g ^ sw) << 2);          // tile0 chunk g
    const int wr1 = pw + (((4 + g) ^ sw) << 2);    // tile1 chunk 4+g
    const int rdo = pw + (((2 * g) ^ sw) << 2);    // read chunks 2g,2g+1

    const unsigned short* kp0 = kb + (size_t)(jbeg + li) * DH + g * 8;
    const unsigned short* kp1 = kp0 + 16 * DH;
    const unsigned short* vp0 = vb + (size_t)li * NN + jbeg + g * 8;
    const unsigned short* vp1 = vp0 + 16 * NN;

    bf16x8 kf0 = *(const bf16x8*)kp0;
    bf16x8 kf1 = *(const bf16x8*)kp1;
    bf16x8 vf0 = *(const bf16x8*)vp0;
    bf16x8 vf1 = *(const bf16x8*)vp1;

#pragma unroll 1
    for (int it = 0; it < NITER; ++it) {
        const f32x4 z = {0.f, 0.f, 0.f, 0.f};
        f32x4 s0[NFRAG], s1[NFRAG];
#pragma unroll
        for (int f = 0; f < NFRAG; ++f)
            s0[f] = __builtin_amdgcn_mfma_f32_16x16x32_bf16(kf0, qf[f], z, 0, 0, 0);
#pragma unroll
        for (int f = 0; f < NFRAG; ++f)
            s1[f] = __builtin_amdgcn_mfma_f32_16x16x32_bf16(kf1, qf[f], z, 0, 0, 0);

        // kf dead -> reload in place for next iter (last-iter over-read
        // stays inside the workspace)
        kp0 += 32 * DH; kp1 += 32 * DH;
        kf0 = *(const bf16x8*)kp0;
        kf1 = *(const bf16x8*)kp1;

        float p0[NFRAG][4], p1[NFRAG][4];
#pragma unroll
        for (int f = 0; f < NFRAG; ++f)
#pragma unroll
            for (int r = 0; r < 4; ++r) {
                p0[f][r] = __builtin_amdgcn_exp2f(s0[f][r]);
                p1[f][r] = __builtin_amdgcn_exp2f(s1[f][r]);
            }

#pragma unroll
        for (int f = 0; f < NFRAG; ++f) {
            uint2 wa, wb;
            wa.x = pack_trunc(p0[f][0], p0[f][1]);
            wa.y = pack_trunc(p0[f][2], p0[f][3]);
            wb.x = pack_trunc(p1[f][0], p1[f][1]);
            wb.y = pack_trunc(p1[f][2], p1[f][3]);
            *(uint2*)&Pl[wave][f][wr0] = wa;
            *(uint2*)&Pl[wave][f][wr1] = wb;
        }

        bf16x8 pf[NFRAG];
#pragma unroll
        for (int f = 0; f < NFRAG; ++f)
            pf[f] = *(const bf16x8*)&Pl[wave][f][rdo];

#pragma unroll
        for (int f = 0; f < NFRAG; ++f)
            O0[f] = __builtin_amdgcn_mfma_f32_16x16x32_bf16(vf0,  pf[f], O0[f], 0, 0, 0);
#pragma unroll
        for (int f = 0; f < NFRAG; ++f)
            O1[f] = __builtin_amdgcn_mfma_f32_16x16x32_bf16(vf1,  pf[f], O1[f], 0, 0, 0);
#pragma unroll
        for (int f = 0; f < NFRAG; ++f)
            Ls[f] = __builtin_amdgcn_mfma_f32_16x16x32_bf16(ones, pf[f], Ls[f], 0, 0, 0);

        // vf dead -> reload in place for next iter
        vp0 += 32; vp1 += 32;
        vf0 = *(const bf16x8*)vp0;
        vf1 = *(const bf16x8*)vp1;
    }

    // epilogue: Op[part][bh][d][n] bf16 (O^T C-layout: col i=li, row d)
    unsigned short* ob = Op + (size_t)part * SEG + (size_t)bh * DH * NN + i0 + li;
#pragma unroll
    for (int f = 0; f < NFRAG; ++f) {
        unsigned short* obf = ob + f * 16;
#pragma unroll
        for (int r = 0; r < 4; ++r) {
            obf[(size_t)(4 * g + r)      * NN] = f2bf(O0[f][r]);
            obf[(size_t)(16 + 4 * g + r) * NN] = f2bf(O1[f][r]);
        }
    }
    if (g == 0) {
        float* lpb = Lp + (size_t)part * LSEG + (size_t)bh * NN + i0 + li;
#pragma unroll
        for (int f = 0; f < NFRAG; ++f)
            lpb[f * 16] = Ls[f][0];
    }
}

// ---------------------------------------------------------------------------
// Kernel 3: output projection, 128x128-tile bf16 MFMA GEMM (r10 winner with
// Bs bank-conflict swizzle).  Untouched.
// ---------------------------------------------------------------------------
__global__ __launch_bounds__(256) void out_proj_kernel(
    const unsigned short* __restrict__ Op, const float* __restrict__ Lp,
    const float* __restrict__ w, const float* __restrict__ bias,
    float* __restrict__ y)
{
    __shared__ unsigned short As[128 * 40];
    __shared__ unsigned short Bs[128 * 40];
    __shared__ float Linv[4][128];
    // XCD-grouped decode: Lb in [0,288)
    const int Lb   = (int)blockIdx.x;
    const int xcd  = Lb & 7;
    const int t    = Lb >> 3;            // 0..35
    const int so_  = t % 2;              // o-block varies fastest within XCD
    const int gl   = t / 2;              // 0..17
    const int group = gl * 8 + xcd;      // 0..143
    const int nb   = group % 18;
    const int b    = group / 18;
    const int n0 = nb * 128;
    const int o0 = so_ * 128;

    const int tid  = (int)threadIdx.x;
    const int wave = tid >> 6;
    const int lane = tid & 63;
    const int li   = lane & 15;
    const int g    = lane >> 4;
    const int wm = (wave & 1) * 64;
    const int wn = (wave >> 1) * 64;

    const int aco = (tid & 7) * 4;
    const int aor = tid >> 3;
    const int n4  = (tid & 31) * 4;   // B staging: n base
    const int d4  = (tid >> 5) * 4;   // B staging: d base (global load)
    const int l5   = tid & 31;
    const int bkey = (l5 ^ (l5 >> 2)) & 3;
    const int bsw  = ((((tid >> 6) ^ bkey) << 1) | ((tid >> 5) & 1)) << 2;

    {
        const int h = tid >> 6, nb2 = tid & 63;
#pragma unroll
        for (int half = 0; half < 2; ++half) {
            const int n = nb2 + 64 * half;
            float s = 0.f;
#pragma unroll
            for (int p = 0; p < PPARTS; ++p)
                s += Lp[(size_t)p * LSEG + (size_t)(b * NH + h) * NN + n0 + n];
            Linv[h][n] = 1.0f / s;
        }
    }

    f32x4 acc[4][4];
#pragma unroll
    for (int i = 0; i < 4; ++i)
#pragma unroll
        for (int j = 0; j < 4; ++j) acc[i][j] = (f32x4){0.f, 0.f, 0.f, 0.f};

    float4 wv[4];
    uint2  ov[PPARTS][4];
#pragma unroll
    for (int r = 0; r < 4; ++r)
        wv[r] = *(const float4*)&w[(size_t)(o0 + aor + 32 * r) * HIDC + aco];
    {
        const size_t bh0 = (size_t)(b * NH);
#pragma unroll
        for (int p = 0; p < PPARTS; ++p)
#pragma unroll
            for (int dd = 0; dd < 4; ++dd)
                ov[p][dd] = *(const uint2*)&Op[(size_t)p * SEG
                              + (bh0 * DH + d4 + dd) * (size_t)NN + n0 + n4];
    }

    for (int k0 = 0; k0 < HIDC; k0 += 32) {
        __syncthreads();
#pragma unroll
        for (int r = 0; r < 4; ++r) {
            uint2 pk;
            pk.x = (unsigned)f2bf(wv[r].x) | ((unsigned)f2bf(wv[r].y) << 16);
            pk.y = (unsigned)f2bf(wv[r].z) | ((unsigned)f2bf(wv[r].w) << 16);
            *(uint2*)&As[(aor + 32 * r) * 40 + aco] = pk;
        }
        const int h = k0 >> 5;                      // BK=32 == one head
        {
            float s[4][4];
#pragma unroll
            for (int dd = 0; dd < 4; ++dd)
#pragma unroll
                for (int j = 0; j < 4; ++j) s[dd][j] = 0.f;
#pragma unroll
            for (int p = 0; p < PPARTS; ++p) {
#pragma unroll
                for (int dd = 0; dd < 4; ++dd) {
                    const uint2 u = ov[p][dd];
                    s[dd][0] += bflo(u.x); s[dd][1] += bfhi(u.x);
                    s[dd][2] += bflo(u.y); s[dd][3] += bfhi(u.y);
                }
            }
#pragma unroll
            for (int j = 0; j < 4; ++j) {
                const float lv = Linv[h][n4 + j];
                uint2 pk;
                pk.x = (unsigned)f2bf(s[0][j] * lv) | ((unsigned)f2bf(s[1][j] * lv) << 16);
                pk.y = (unsigned)f2bf(s[2][j] * lv) | ((unsigned)f2bf(s[3][j] * lv) << 16);
                *(uint2*)&Bs[(n4 + j) * 40 + bsw] = pk;
            }
        }
        __syncthreads();

        // prefetch next K-step (clamped on last iter; values dead)
        const int kn = (k0 + 32 < HIDC) ? (k0 + 32) : k0;
        const size_t bhn = (size_t)(b * NH + (kn >> 5));
#pragma unroll
        for (int r = 0; r < 4; ++r)
            wv[r] = *(const float4*)&w[(size_t)(o0 + aor + 32 * r) * HIDC + kn + aco];
#pragma unroll
        for (int p = 0; p < PPARTS; ++p)
#pragma unroll
            for (int dd = 0; dd < 4; ++dd)
                ov[p][dd] = *(const uint2*)&Op[(size_t)p * SEG
                              + (bhn * DH + d4 + dd) * (size_t)NN + n0 + n4];

        bf16x8 af[4], bfr[4];
#pragma unroll
        for (int mt = 0; mt < 4; ++mt)
            af[mt] = *(const bf16x8*)&As[(wm + mt * 16 + li) * 40 + g * 8];
#pragma unroll
        for (int nt = 0; nt < 4; ++nt) {
            const int rr = wn + nt * 16 + li;
            const int rm = rr >> 2;
            bfr[nt] = *(const bf16x8*)&Bs[rr * 40 + ((g ^ ((rm ^ (rm >> 2)) & 3)) << 3)];
        }
#pragma unroll
        for (int mt = 0; mt < 4; ++mt)
#pragma unroll
            for (int nt = 0; nt < 4; ++nt)
                acc[mt][nt] = __builtin_amdgcn_mfma_f32_16x16x32_bf16(
                    af[mt], bfr[nt], acc[mt][nt], 0, 0, 0);
    }

#pragma unroll
    for (int mt = 0; mt < 4; ++mt) {
        const int ob = o0 + wm + mt * 16 + g * 4;
        const float b0 = bias[ob], b1 = bias[ob + 1], b2 = bias[ob + 2], b3 = bias[ob + 3];
#pragma unroll
        for (int nt = 0; nt < 4; ++nt) {
            const int n = n0 + wn + nt * 16 + li;
            const f32x4 a = acc[mt][nt];
            float* yb = y + ((size_t)(b * CDIM + ob)) * NN + n;
            yb[0]              = a[0] + b0;
            yb[(size_t)NN]     = a[1] + b1;
            yb[(size_t)2 * NN] = a[2] + b2;
            yb[(size_t)3 * NN] = a[3] + b3;
        }
    }
}

// ---------------------------------------------------------------------------
extern "C" void kernel_launch(void* const* d_in, const int* in_sizes, int n_in,
                              void* d_out, int out_size, void* d_ws, size_t ws_size,
                              hipStream_t stream)
{
    (void)in_sizes; (void)n_in; (void)out_size; (void)ws_size;
    const float* x     = (const float*)d_in[0];
    const float* w_qkv = (const float*)d_in[1];
    const float* w_out = (const float*)d_in[2];
    const float* b_out = (const float*)d_in[3];
    float* y = (float*)d_out;

    unsigned short* qt  = (unsigned short*)d_ws;
    unsigned short* kt  = qt + SEG;
    unsigned short* vtT = kt + SEG;
    unsigned short* Op  = vtT + SEG;                     // PPARTS x SEG bf16
    float* Lp = (float*)(Op + (size_t)PPARTS * SEG);     // PPARTS x LSEG fp32

    qkv_proj_kernel<<<dim3(432), 256, 0, stream>>>(x, w_qkv, qt, kt, vtT);

    attn_kernel<<<dim3(768), 256, 0, stream>>>(qt, kt, vtT, Op, Lp);

    out_proj_kernel<<<dim3(288), 256, 0, stream>>>(Op, Lp, w_out, b_out, y);
}